// Round 1
// baseline (319.492 us; speedup 1.0000x reference)
//
#include <hip/hip_runtime.h>
#include <hip/hip_bf16.h>

#define NB    16
#define NPT   4096
#define NSRC  1024
#define ND1   128
#define ND2   256
#define NCIN  384
#define NCMID 256
#define NCOUT 128
#define BNTOT (NB * NPT)   // 65536 points
#define BN_EPS 1e-5f

typedef float f32x4 __attribute__((ext_vector_type(4)));
typedef short bf16x8 __attribute__((ext_vector_type(8)));

union PK8 { unsigned short u[8]; uint4 q; };

static __device__ __forceinline__ unsigned short f2bf(float f) {
  __hip_bfloat16 h = __float2bfloat16(f);
  return __builtin_bit_cast(unsigned short, h);
}

// ---------------- kNN: 3 nearest neighbors + inverse-distance weights ----------------
__global__ __launch_bounds__(256) void knn_kernel(
    const float* __restrict__ xyz1, const float* __restrict__ xyz2,
    int* __restrict__ nidx, float* __restrict__ nwgt)
{
  __shared__ float s2[NSRC * 3];   // 12 KB: whole xyz2 slab for this batch
  const int b = blockIdx.x >> 4;        // 16 chunks of 256 points per batch
  const int chunk = blockIdx.x & 15;
  const int tid = threadIdx.x;
  for (int i = tid; i < NSRC * 3; i += 256) s2[i] = xyz2[b * NSRC * 3 + i];
  __syncthreads();
  const int n = chunk * 256 + tid;
  const size_t p = (size_t)b * NPT + n;
  const float x = xyz1[p * 3 + 0], y = xyz1[p * 3 + 1], z = xyz1[p * 3 + 2];
  float t0 = 3.4e38f, t1 = 3.4e38f, t2 = 3.4e38f;
  int j0 = 0, j1 = 0, j2 = 0;
  for (int s = 0; s < NSRC; ++s) {
    const float dx = x - s2[s * 3 + 0];
    const float dy = y - s2[s * 3 + 1];
    const float dz = z - s2[s * 3 + 2];
    const float d = dx * dx + dy * dy + dz * dz;
    if (d < t2) {
      if (d < t1) {
        t2 = t1; j2 = j1;
        if (d < t0) { t1 = t0; j1 = j0; t0 = d; j0 = s; }
        else        { t1 = d;  j1 = s; }
      } else { t2 = d; j2 = s; }
    }
  }
  float w0 = 1.f / (t0 + 1e-8f), w1 = 1.f / (t1 + 1e-8f), w2 = 1.f / (t2 + 1e-8f);
  const float inv = 1.f / (w0 + w1 + w2);
  nidx[p * 3 + 0] = j0; nidx[p * 3 + 1] = j1; nidx[p * 3 + 2] = j2;
  nwgt[p * 3 + 0] = w0 * inv; nwgt[p * 3 + 1] = w1 * inv; nwgt[p * 3 + 2] = w2 * inv;
}

// ---------------- weighted 3-NN interpolation: interp[pt][0..255] ----------------
__global__ __launch_bounds__(256) void interp_kernel(
    const float* __restrict__ points2, const int* __restrict__ nidx,
    const float* __restrict__ nwgt, float* __restrict__ interp)
{
  const int tid = threadIdx.x;
  const int pt = blockIdx.x * 4 + (tid >> 6);   // 4 points per block
  const int c4 = tid & 63;                      // float4 channel index (64*4 = 256)
  const int b = pt >> 12;                       // NPT = 4096
  const float4* p2 = (const float4*)(points2 + (size_t)b * NSRC * ND2);
  const int j0 = nidx[pt * 3 + 0], j1 = nidx[pt * 3 + 1], j2 = nidx[pt * 3 + 2];
  const float w0 = nwgt[pt * 3 + 0], w1 = nwgt[pt * 3 + 1], w2 = nwgt[pt * 3 + 2];
  const float4 va = p2[j0 * 64 + c4];
  const float4 vb = p2[j1 * 64 + c4];
  const float4 vc = p2[j2 * 64 + c4];
  float4 r;
  r.x = w0 * va.x + w1 * vb.x + w2 * vc.x;
  r.y = w0 * va.y + w1 * vb.y + w2 * vc.y;
  r.z = w0 * va.z + w1 * vb.z + w2 * vc.z;
  r.w = w0 * va.w + w1 * vb.w + w2 * vc.w;
  ((float4*)interp)[(size_t)pt * 64 + c4] = r;
}

// ---------------- GEMM1: h1[pt][c] = b1[c] + sum_k X[pt][k] * W1[c][k] ----------------
// X[pt][k] = points1[pt][k] (k<128) else interp[pt][k-128].  M=65536, N=256, K=384.
// Block: 4 waves, Mtile=64, Ntile=256 (full) -> X read exactly once from HBM.
__global__ __launch_bounds__(256) void gemm1_kernel(
    const float* __restrict__ points1, const float* __restrict__ interp,
    const float* __restrict__ W1, const float* __restrict__ bias1,
    float* __restrict__ h1)
{
  __shared__ unsigned short sX[64][40];      // 32 k + 8 pad
  __shared__ unsigned short sW[NCMID][40];
  const int tid = threadIdx.x;
  const int lane = tid & 63;
  const int wave = tid >> 6;
  const int ptBase = blockIdx.x * 64;

  f32x4 acc[16];
#pragma unroll
  for (int j = 0; j < 16; ++j)
#pragma unroll
    for (int q = 0; q < 4; ++q) acc[j][q] = 0.0f;

  const int xr = tid >> 2;            // 0..63  point row
  const int xks = (tid & 3) * 8;      // 0,8,16,24 k-segment

  for (int kt = 0; kt < 12; ++kt) {
    const int k0 = kt * 32;
    { // stage X tile (64 pts x 32 k), fp32 -> bf16
      const int k = k0 + xks;
      const int pt = ptBase + xr;
      const float* src = (k < ND1)
          ? (points1 + (size_t)pt * ND1 + k)
          : (interp + (size_t)pt * ND2 + (k - ND1));
      const float4 va = ((const float4*)src)[0];
      const float4 vb = ((const float4*)src)[1];
      PK8 pk;
      pk.u[0] = f2bf(va.x); pk.u[1] = f2bf(va.y); pk.u[2] = f2bf(va.z); pk.u[3] = f2bf(va.w);
      pk.u[4] = f2bf(vb.x); pk.u[5] = f2bf(vb.y); pk.u[6] = f2bf(vb.z); pk.u[7] = f2bf(vb.w);
      *(uint4*)&sX[xr][xks] = pk.q;
    }
    { // stage W tile (256 ch x 32 k): thread tid = channel row
      const float* wsrc = W1 + (size_t)tid * NCIN + k0;
#pragma unroll
      for (int s = 0; s < 4; ++s) {
        const float4 va = ((const float4*)wsrc)[2 * s];
        const float4 vb = ((const float4*)wsrc)[2 * s + 1];
        PK8 pk;
        pk.u[0] = f2bf(va.x); pk.u[1] = f2bf(va.y); pk.u[2] = f2bf(va.z); pk.u[3] = f2bf(va.w);
        pk.u[4] = f2bf(vb.x); pk.u[5] = f2bf(vb.y); pk.u[6] = f2bf(vb.z); pk.u[7] = f2bf(vb.w);
        *(uint4*)&sW[tid][s * 8] = pk.q;
      }
    }
    __syncthreads();
    const int fr = lane & 15;
    const int kq = (lane >> 4) * 8;
    const bf16x8 af = *(const bf16x8*)&sX[wave * 16 + fr][kq];
#pragma unroll
    for (int j = 0; j < 16; ++j) {
      const bf16x8 bfv = *(const bf16x8*)&sW[j * 16 + fr][kq];
      acc[j] = __builtin_amdgcn_mfma_f32_16x16x32_bf16(af, bfv, acc[j], 0, 0, 0);
    }
    __syncthreads();
  }

  // epilogue: D layout col=lane&15, row=(lane>>4)*4+reg   [verified m89/m91]
  const int col = lane & 15;
  const int r0 = (lane >> 4) * 4;
#pragma unroll
  for (int j = 0; j < 16; ++j) {
    const int ch = j * 16 + col;
    const float bb = bias1[ch];
#pragma unroll
    for (int q = 0; q < 4; ++q) {
      const int pt = ptBase + wave * 16 + r0 + q;
      h1[(size_t)pt * NCMID + ch] = acc[j][q] + bb;
    }
  }
}

// ---------------- per-channel column sums (for BN batch stats) ----------------
template <int C, int R>
__global__ void colsum_kernel(const float* __restrict__ x,
                              float* __restrict__ sum, float* __restrict__ sumsq)
{
  const int t = threadIdx.x;              // C threads, thread = channel
  const size_t r0 = (size_t)blockIdx.x * R;
  float s = 0.f, s2 = 0.f;
  for (int r = 0; r < R; ++r) {
    const float v = x[(r0 + r) * C + t];
    s += v; s2 += v * v;
  }
  atomicAdd(&sum[t], s);
  atomicAdd(&sumsq[t], s2);
}

// ---------------- fold BN into per-channel affine: y = a*x + d ----------------
template <int C>
__global__ void stats_kernel(const float* __restrict__ sum, const float* __restrict__ sumsq,
                             const float* __restrict__ g, const float* __restrict__ be,
                             float* __restrict__ a, float* __restrict__ d)
{
  const int c = threadIdx.x;
  const float mean = sum[c] * (1.0f / BNTOT);
  const float var = sumsq[c] * (1.0f / BNTOT) - mean * mean;
  const float inv = rsqrtf(var + BN_EPS);
  const float ac = g[c] * inv;
  a[c] = ac;
  d[c] = be[c] - mean * ac;
}

// ---------------- GEMM2: out_raw[pt][c] = b2[c] + sum_k relu(a1[k]*h1[pt][k]+d1[k]) * W2[c][k]
__global__ __launch_bounds__(256) void gemm2_kernel(
    const float* __restrict__ h1, const float* __restrict__ W2,
    const float* __restrict__ bias2, const float* __restrict__ aff_a,
    const float* __restrict__ aff_d, float* __restrict__ out)
{
  __shared__ unsigned short sA[64][40];
  __shared__ unsigned short sB[NCOUT][40];
  __shared__ float sa[NCMID], sd[NCMID];
  const int tid = threadIdx.x;
  const int lane = tid & 63;
  const int wave = tid >> 6;
  const int ptBase = blockIdx.x * 64;
  sa[tid] = aff_a[tid];
  sd[tid] = aff_d[tid];
  __syncthreads();

  f32x4 acc[8];
#pragma unroll
  for (int j = 0; j < 8; ++j)
#pragma unroll
    for (int q = 0; q < 4; ++q) acc[j][q] = 0.0f;

  const int xr = tid >> 2;
  const int xks = (tid & 3) * 8;
  const int wr = tid & 127;
  const int wh = (tid >> 7) * 16;

  for (int kt = 0; kt < 8; ++kt) {
    const int k0 = kt * 32;
    { // stage A: BN1-affine + ReLU fused, fp32 -> bf16
      const float* src = h1 + (size_t)(ptBase + xr) * NCMID + k0 + xks;
      const float4 va = ((const float4*)src)[0];
      const float4 vb = ((const float4*)src)[1];
      float v[8] = {va.x, va.y, va.z, va.w, vb.x, vb.y, vb.z, vb.w};
      PK8 pk;
#pragma unroll
      for (int j = 0; j < 8; ++j) {
        const int c = k0 + xks + j;
        pk.u[j] = f2bf(fmaxf(0.f, sa[c] * v[j] + sd[c]));
      }
      *(uint4*)&sA[xr][xks] = pk.q;
    }
    { // stage B from W2: 128 rows x 32 k, two threads per row
      const float* wsrc = W2 + (size_t)wr * NCMID + k0 + wh;
      const float4 va = ((const float4*)wsrc)[0];
      const float4 vb = ((const float4*)wsrc)[1];
      const float4 vc = ((const float4*)wsrc)[2];
      const float4 vd = ((const float4*)wsrc)[3];
      PK8 pk;
      pk.u[0] = f2bf(va.x); pk.u[1] = f2bf(va.y); pk.u[2] = f2bf(va.z); pk.u[3] = f2bf(va.w);
      pk.u[4] = f2bf(vb.x); pk.u[5] = f2bf(vb.y); pk.u[6] = f2bf(vb.z); pk.u[7] = f2bf(vb.w);
      *(uint4*)&sB[wr][wh] = pk.q;
      pk.u[0] = f2bf(vc.x); pk.u[1] = f2bf(vc.y); pk.u[2] = f2bf(vc.z); pk.u[3] = f2bf(vc.w);
      pk.u[4] = f2bf(vd.x); pk.u[5] = f2bf(vd.y); pk.u[6] = f2bf(vd.z); pk.u[7] = f2bf(vd.w);
      *(uint4*)&sB[wr][wh + 8] = pk.q;
    }
    __syncthreads();
    const int fr = lane & 15;
    const int kq = (lane >> 4) * 8;
    const bf16x8 af = *(const bf16x8*)&sA[wave * 16 + fr][kq];
#pragma unroll
    for (int j = 0; j < 8; ++j) {
      const bf16x8 bfv = *(const bf16x8*)&sB[j * 16 + fr][kq];
      acc[j] = __builtin_amdgcn_mfma_f32_16x16x32_bf16(af, bfv, acc[j], 0, 0, 0);
    }
    __syncthreads();
  }

  const int col = lane & 15;
  const int r0 = (lane >> 4) * 4;
#pragma unroll
  for (int j = 0; j < 8; ++j) {
    const int ch = j * 16 + col;
    const float bb = bias2[ch];
#pragma unroll
    for (int q = 0; q < 4; ++q) {
      const int pt = ptBase + wave * 16 + r0 + q;
      out[(size_t)pt * NCOUT + ch] = acc[j][q] + bb;
    }
  }
}

// ---------------- final: in-place BN2-affine + ReLU on d_out ----------------
__global__ __launch_bounds__(256) void final_kernel(
    float* __restrict__ out, const float* __restrict__ a2, const float* __restrict__ d2)
{
  const int total4 = BNTOT * NCOUT / 4;   // 2,097,152 float4s
  for (int i = blockIdx.x * blockDim.x + threadIdx.x; i < total4;
       i += gridDim.x * blockDim.x) {
    float4 v = ((float4*)out)[i];
    const int c = (i & 31) * 4;           // 32 float4 per 128-ch row
    v.x = fmaxf(0.f, a2[c + 0] * v.x + d2[c + 0]);
    v.y = fmaxf(0.f, a2[c + 1] * v.y + d2[c + 1]);
    v.z = fmaxf(0.f, a2[c + 2] * v.z + d2[c + 2]);
    v.w = fmaxf(0.f, a2[c + 3] * v.w + d2[c + 3]);
    ((float4*)out)[i] = v;
  }
}

extern "C" void kernel_launch(void* const* d_in, const int* in_sizes, int n_in,
                              void* d_out, int out_size, void* d_ws, size_t ws_size,
                              hipStream_t stream) {
  const float* xyz1    = (const float*)d_in[0];
  const float* xyz2    = (const float*)d_in[1];
  const float* points1 = (const float*)d_in[2];
  const float* points2 = (const float*)d_in[3];
  const float* W1      = (const float*)d_in[4];
  const float* b1      = (const float*)d_in[5];
  const float* g1      = (const float*)d_in[6];
  const float* be1     = (const float*)d_in[7];
  const float* W2      = (const float*)d_in[8];
  const float* b2      = (const float*)d_in[9];
  const float* g2      = (const float*)d_in[10];
  const float* be2     = (const float*)d_in[11];
  float* out = (float*)d_out;

  char* ws = (char*)d_ws;
  const size_t interp_bytes = (size_t)BNTOT * ND2 * sizeof(float);    // 64 MB
  const size_t h1_bytes     = (size_t)BNTOT * NCMID * sizeof(float);  // 64 MB
  const size_t idx_bytes    = (size_t)BNTOT * 3 * sizeof(int);        // 768 KB
  float* interp = (float*)ws;
  float* h1     = (float*)(ws + interp_bytes);
  int*   nidx   = (int*)(ws + interp_bytes + h1_bytes);
  float* nwgt   = (float*)(ws + interp_bytes + h1_bytes + idx_bytes);
  float* stats  = (float*)(ws + interp_bytes + h1_bytes + 2 * idx_bytes);
  // stats layout: sum1[256] sq1[256] sum2[128] sq2[128] | a1[256] dd1[256] a2[128] dd2[128]
  float* sum1 = stats;
  float* sq1  = stats + 256;
  float* sum2 = stats + 512;
  float* sq2  = stats + 640;
  float* a1   = stats + 768;
  float* dd1  = stats + 1024;
  float* a2   = stats + 1280;
  float* dd2  = stats + 1408;

  // zero the accumulated sums (ws is poisoned, not re-zeroed between replays)
  hipMemsetAsync(stats, 0, 768 * sizeof(float), stream);

  knn_kernel<<<NB * (NPT / 256), 256, 0, stream>>>(xyz1, xyz2, nidx, nwgt);
  interp_kernel<<<BNTOT / 4, 256, 0, stream>>>(points2, nidx, nwgt, interp);
  gemm1_kernel<<<BNTOT / 64, 256, 0, stream>>>(points1, interp, W1, b1, h1);
  colsum_kernel<NCMID, 256><<<BNTOT / 256, NCMID, 0, stream>>>(h1, sum1, sq1);
  stats_kernel<NCMID><<<1, NCMID, 0, stream>>>(sum1, sq1, g1, be1, a1, dd1);
  gemm2_kernel<<<BNTOT / 64, 256, 0, stream>>>(h1, W2, b2, a1, dd1, out);
  colsum_kernel<NCOUT, 128><<<BNTOT / 128, NCOUT, 0, stream>>>(out, sum2, sq2);
  stats_kernel<NCOUT><<<1, NCOUT, 0, stream>>>(sum2, sq2, g2, be2, a2, dd2);
  final_kernel<<<2048, 256, 0, stream>>>(out, a2, dd2);
}

// Round 3
// 213.626 us; speedup vs baseline: 1.4956x; 1.4956x over previous
//
#include <hip/hip_runtime.h>
#include <hip/hip_bf16.h>

#define NB    16
#define NPT   4096
#define NSRC  1024
#define ND1   128
#define ND2   256
#define NCIN  384
#define NCMID 256
#define NCOUT 128
#define BNTOT (NB * NPT)   // 65536 points
#define BN_EPS 1e-5f

typedef float f32x4 __attribute__((ext_vector_type(4)));
typedef short bf16x8 __attribute__((ext_vector_type(8)));
typedef unsigned int uint;

union PK8 { unsigned short u[8]; uint4 q; };

static __device__ __forceinline__ unsigned short f2bf(float f) {
  __hip_bfloat16 h = __float2bfloat16(f);
  return __builtin_bit_cast(unsigned short, h);
}

// total order: (d, idx) with ties -> lower index (matches lax.top_k)
static __device__ __forceinline__ bool prec(float da, int ia, float db, int ib) {
  return (da < db) || (da == db && ia < ib);
}

// ---------------- kNN: 3 nearest neighbors + inverse-distance weights ----------------
// 4 lanes per point (lane q scans sources q*256..q*256+255). Branchless top-3 with
// EXACT (float,int) pairs: v_cmp + cndmask network; ties keep incumbent (lower idx).
__global__ __launch_bounds__(256) void knn_kernel(
    const float* __restrict__ xyz1, const float* __restrict__ xyz2,
    int* __restrict__ nidx, float* __restrict__ nwgt)
{
  // slabs of float4 (-2x, -2y, -2z, |b|^2); stride 257 float4s skews the 4
  // quarters to disjoint 4-bank windows -> conflict-free broadcast ds_read_b128.
  __shared__ float4 s2t[4 * 257];
  const int tid = threadIdx.x;
  const int b = blockIdx.x >> 6;         // 64 points per block, 64 blocks per batch
  // stage + transform xyz2: thread t loads sources 4t..4t+3 (48 B = 3 float4)
  {
    const float* src = xyz2 + (size_t)b * NSRC * 3 + tid * 12;
    const float4 l0 = ((const float4*)src)[0];
    const float4 l1 = ((const float4*)src)[1];
    const float4 l2 = ((const float4*)src)[2];
    const float xs[4] = {l0.x, l0.w, l1.z, l2.y};
    const float ys[4] = {l0.y, l1.x, l1.w, l2.z};
    const float zs[4] = {l0.z, l1.y, l2.x, l2.w};
    const int qq = tid >> 6;
    const int ibase = (tid & 63) * 4;
#pragma unroll
    for (int u = 0; u < 4; ++u) {
      const float c = xs[u] * xs[u] + ys[u] * ys[u] + zs[u] * zs[u];
      float4 v;
      v.x = -2.0f * xs[u]; v.y = -2.0f * ys[u]; v.z = -2.0f * zs[u]; v.w = c;
      s2t[qq * 257 + ibase + u] = v;
    }
  }
  __syncthreads();

  const int p = blockIdx.x * 64 + (tid >> 2);       // global point id
  const int q = tid & 3;                            // source quarter
  const float ax = xyz1[(size_t)p * 3 + 0];
  const float ay = xyz1[(size_t)p * 3 + 1];
  const float az = xyz1[(size_t)p * 3 + 2];
  const float a2 = ax * ax + ay * ay + az * az;
  const float4* slab = &s2t[q * 257];
  const int qbase = q * 256;

  const float INF = 3.4e38f;
  // two interleaved top-3 chains (A: even scan slots, B: odd) to shorten the
  // dependent cndmask chain; merged exactly below.
  float ta0 = INF, ta1 = INF, ta2 = INF; int ja0 = 0, ja1 = 0, ja2 = 0;
  float tb0 = INF, tb1 = INF, tb2 = INF; int jb0 = 0, jb1 = 0, jb2 = 0;

#define INS3(t0, t1, t2, j0, j1, j2, d, idx)                                   \
  {                                                                            \
    const bool c0 = (d) < t0;                                                  \
    const float h0 = c0 ? t0 : (d); const int hj0 = c0 ? j0 : (idx);           \
    t0 = c0 ? (d) : t0;             j0 = c0 ? (idx) : j0;                      \
    const bool c1 = h0 < t1;                                                   \
    const float h1 = c1 ? t1 : h0;  const int hj1 = c1 ? j1 : hj0;             \
    t1 = c1 ? h0 : t1;              j1 = c1 ? hj0 : j1;                        \
    const bool c2 = h1 < t2;                                                   \
    t2 = c2 ? h1 : t2;              j2 = c2 ? hj1 : j2;                        \
  }

  for (int i = 0; i < 256; i += 2) {
    const float4 va = slab[i];
    float da = va.w + a2;
    da = fmaf(va.x, ax, da); da = fmaf(va.y, ay, da); da = fmaf(va.z, az, da);
    INS3(ta0, ta1, ta2, ja0, ja1, ja2, da, qbase + i);
    const float4 vb = slab[i + 1];
    float db = vb.w + a2;
    db = fmaf(vb.x, ax, db); db = fmaf(vb.y, ay, db); db = fmaf(vb.z, az, db);
    INS3(tb0, tb1, tb2, jb0, jb1, jb2, db, qbase + i + 1);
  }

  // exact merge of two sorted triples -> top-3 (pair comparator, tie -> lower idx)
#define MERGE3(d0, j0, d1, j1, d2, j2, e0, i0, e1, i1, e2, i2)                 \
  {                                                                            \
    const bool p0 = prec(d0, j0, e0, i0);                                      \
    const float l0d = p0 ? e0 : d0; const int l0j = p0 ? i0 : j0;              \
    const float r0d = p0 ? d0 : e0; const int r0j = p0 ? j0 : i0;              \
    const bool p1 = prec(d1, j1, e1, i1);                                      \
    const float w1d = p1 ? d1 : e1; const int w1j = p1 ? j1 : i1;              \
    const bool pr1 = prec(l0d, l0j, w1d, w1j);                                 \
    const float r1d = pr1 ? l0d : w1d; const int r1j = pr1 ? l0j : w1j;        \
    const float q1d = pr1 ? w1d : l0d; const int q1j = pr1 ? w1j : l0j;        \
    const bool p2 = prec(d2, j2, e2, i2);                                      \
    const float w2d = p2 ? d2 : e2; const int w2j = p2 ? j2 : i2;              \
    const bool pr2 = prec(q1d, q1j, w2d, w2j);                                 \
    const float r2d = pr2 ? q1d : w2d; const int r2j = pr2 ? q1j : w2j;        \
    d0 = r0d; j0 = r0j; d1 = r1d; j1 = r1j; d2 = r2d; j2 = r2j;                \
  }

  MERGE3(ta0, ja0, ta1, ja1, ta2, ja2, tb0, jb0, tb1, jb1, tb2, jb2);

  // merge the 4 lanes' triples (xor 1, then xor 2) — all lanes converge
#pragma unroll
  for (int m = 1; m <= 2; m <<= 1) {
    float e0 = __shfl_xor(ta0, m), e1 = __shfl_xor(ta1, m), e2 = __shfl_xor(ta2, m);
    int i0 = __shfl_xor(ja0, m), i1 = __shfl_xor(ja1, m), i2 = __shfl_xor(ja2, m);
    MERGE3(ta0, ja0, ta1, ja1, ta2, ja2, e0, i0, e1, i1, e2, i2);
  }

  if (q == 0) {
    float w0 = 1.f / (ta0 + 1e-8f), w1 = 1.f / (ta1 + 1e-8f), w2 = 1.f / (ta2 + 1e-8f);
    const float inv = 1.f / (w0 + w1 + w2);
    nidx[(size_t)p * 3 + 0] = ja0;
    nidx[(size_t)p * 3 + 1] = ja1;
    nidx[(size_t)p * 3 + 2] = ja2;
    nwgt[(size_t)p * 3 + 0] = w0 * inv;
    nwgt[(size_t)p * 3 + 1] = w1 * inv;
    nwgt[(size_t)p * 3 + 2] = w2 * inv;
  }
#undef INS3
#undef MERGE3
}

// ---------------- weighted 3-NN interpolation: interp[pt][0..255] ----------------
__global__ __launch_bounds__(256) void interp_kernel(
    const float* __restrict__ points2, const int* __restrict__ nidx,
    const float* __restrict__ nwgt, float* __restrict__ interp)
{
  const int tid = threadIdx.x;
  const int pt = blockIdx.x * 4 + (tid >> 6);   // 4 points per block
  const int c4 = tid & 63;                      // float4 channel index (64*4 = 256)
  const int b = pt >> 12;                       // NPT = 4096
  const float4* p2 = (const float4*)(points2 + (size_t)b * NSRC * ND2);
  const int j0 = nidx[pt * 3 + 0], j1 = nidx[pt * 3 + 1], j2 = nidx[pt * 3 + 2];
  const float w0 = nwgt[pt * 3 + 0], w1 = nwgt[pt * 3 + 1], w2 = nwgt[pt * 3 + 2];
  const float4 va = p2[j0 * 64 + c4];
  const float4 vb = p2[j1 * 64 + c4];
  const float4 vc = p2[j2 * 64 + c4];
  float4 r;
  r.x = w0 * va.x + w1 * vb.x + w2 * vc.x;
  r.y = w0 * va.y + w1 * vb.y + w2 * vc.y;
  r.z = w0 * va.z + w1 * vb.z + w2 * vc.z;
  r.w = w0 * va.w + w1 * vb.w + w2 * vc.w;
  ((float4*)interp)[(size_t)pt * 64 + c4] = r;
}

// ---------------- GEMM1: h1[pt][c] = b1[c] + sum_k X[pt][k] * W1[c][k] ----------------
// X[pt][k] = points1[pt][k] (k<128) else interp[pt][k-128].  M=65536, N=256, K=384.
__global__ __launch_bounds__(256) void gemm1_kernel(
    const float* __restrict__ points1, const float* __restrict__ interp,
    const float* __restrict__ W1, const float* __restrict__ bias1,
    float* __restrict__ h1)
{
  __shared__ unsigned short sX[64][40];      // 32 k + 8 pad
  __shared__ unsigned short sW[NCMID][40];
  const int tid = threadIdx.x;
  const int lane = tid & 63;
  const int wave = tid >> 6;
  const int ptBase = blockIdx.x * 64;

  f32x4 acc[16];
#pragma unroll
  for (int j = 0; j < 16; ++j)
#pragma unroll
    for (int q = 0; q < 4; ++q) acc[j][q] = 0.0f;

  const int xr = tid >> 2;            // 0..63  point row
  const int xks = (tid & 3) * 8;      // 0,8,16,24 k-segment

  for (int kt = 0; kt < 12; ++kt) {
    const int k0 = kt * 32;
    { // stage X tile (64 pts x 32 k), fp32 -> bf16
      const int k = k0 + xks;
      const int pt = ptBase + xr;
      const float* src = (k < ND1)
          ? (points1 + (size_t)pt * ND1 + k)
          : (interp + (size_t)pt * ND2 + (k - ND1));
      const float4 va = ((const float4*)src)[0];
      const float4 vb = ((const float4*)src)[1];
      PK8 pk;
      pk.u[0] = f2bf(va.x); pk.u[1] = f2bf(va.y); pk.u[2] = f2bf(va.z); pk.u[3] = f2bf(va.w);
      pk.u[4] = f2bf(vb.x); pk.u[5] = f2bf(vb.y); pk.u[6] = f2bf(vb.z); pk.u[7] = f2bf(vb.w);
      *(uint4*)&sX[xr][xks] = pk.q;
    }
    { // stage W tile (256 ch x 32 k): thread tid = channel row
      const float* wsrc = W1 + (size_t)tid * NCIN + k0;
#pragma unroll
      for (int s = 0; s < 4; ++s) {
        const float4 va = ((const float4*)wsrc)[2 * s];
        const float4 vb = ((const float4*)wsrc)[2 * s + 1];
        PK8 pk;
        pk.u[0] = f2bf(va.x); pk.u[1] = f2bf(va.y); pk.u[2] = f2bf(va.z); pk.u[3] = f2bf(va.w);
        pk.u[4] = f2bf(vb.x); pk.u[5] = f2bf(vb.y); pk.u[6] = f2bf(vb.z); pk.u[7] = f2bf(vb.w);
        *(uint4*)&sW[tid][s * 8] = pk.q;
      }
    }
    __syncthreads();
    const int fr = lane & 15;
    const int kq = (lane >> 4) * 8;
    const bf16x8 af = *(const bf16x8*)&sX[wave * 16 + fr][kq];
#pragma unroll
    for (int j = 0; j < 16; ++j) {
      const bf16x8 bfv = *(const bf16x8*)&sW[j * 16 + fr][kq];
      acc[j] = __builtin_amdgcn_mfma_f32_16x16x32_bf16(af, bfv, acc[j], 0, 0, 0);
    }
    __syncthreads();
  }

  // epilogue: D layout col=lane&15, row=(lane>>4)*4+reg   [verified m89/m91]
  const int col = lane & 15;
  const int r0 = (lane >> 4) * 4;
#pragma unroll
  for (int j = 0; j < 16; ++j) {
    const int ch = j * 16 + col;
    const float bb = bias1[ch];
#pragma unroll
    for (int q = 0; q < 4; ++q) {
      const int pt = ptBase + wave * 16 + r0 + q;
      h1[(size_t)pt * NCMID + ch] = acc[j][q] + bb;
    }
  }
}

// ---------------- per-channel column sums (for BN batch stats) ----------------
template <int C, int R>
__global__ void colsum_kernel(const float* __restrict__ x,
                              float* __restrict__ sum, float* __restrict__ sumsq)
{
  const int t = threadIdx.x;              // C threads, thread = channel
  const size_t r0 = (size_t)blockIdx.x * R;
  float s = 0.f, s2 = 0.f;
  for (int r = 0; r < R; ++r) {
    const float v = x[(r0 + r) * C + t];
    s += v; s2 += v * v;
  }
  atomicAdd(&sum[t], s);
  atomicAdd(&sumsq[t], s2);
}

// ---------------- fold BN into per-channel affine: y = a*x + d ----------------
template <int C>
__global__ void stats_kernel(const float* __restrict__ sum, const float* __restrict__ sumsq,
                             const float* __restrict__ g, const float* __restrict__ be,
                             float* __restrict__ a, float* __restrict__ d)
{
  const int c = threadIdx.x;
  const float mean = sum[c] * (1.0f / BNTOT);
  const float var = sumsq[c] * (1.0f / BNTOT) - mean * mean;
  const float inv = rsqrtf(var + BN_EPS);
  const float ac = g[c] * inv;
  a[c] = ac;
  d[c] = be[c] - mean * ac;
}

// ---------------- GEMM2: out_raw[pt][c] = b2[c] + sum_k relu(a1[k]*h1[pt][k]+d1[k]) * W2[c][k]
__global__ __launch_bounds__(256) void gemm2_kernel(
    const float* __restrict__ h1, const float* __restrict__ W2,
    const float* __restrict__ bias2, const float* __restrict__ aff_a,
    const float* __restrict__ aff_d, float* __restrict__ out)
{
  __shared__ unsigned short sA[64][40];
  __shared__ unsigned short sB[NCOUT][40];
  __shared__ float sa[NCMID], sd[NCMID];
  const int tid = threadIdx.x;
  const int lane = tid & 63;
  const int wave = tid >> 6;
  const int ptBase = blockIdx.x * 64;
  sa[tid] = aff_a[tid];
  sd[tid] = aff_d[tid];
  __syncthreads();

  f32x4 acc[8];
#pragma unroll
  for (int j = 0; j < 8; ++j)
#pragma unroll
    for (int q = 0; q < 4; ++q) acc[j][q] = 0.0f;

  const int xr = tid >> 2;
  const int xks = (tid & 3) * 8;
  const int wr = tid & 127;
  const int wh = (tid >> 7) * 16;

  for (int kt = 0; kt < 8; ++kt) {
    const int k0 = kt * 32;
    { // stage A: BN1-affine + ReLU fused, fp32 -> bf16
      const float* src = h1 + (size_t)(ptBase + xr) * NCMID + k0 + xks;
      const float4 va = ((const float4*)src)[0];
      const float4 vb = ((const float4*)src)[1];
      float v[8] = {va.x, va.y, va.z, va.w, vb.x, vb.y, vb.z, vb.w};
      PK8 pk;
#pragma unroll
      for (int j = 0; j < 8; ++j) {
        const int c = k0 + xks + j;
        pk.u[j] = f2bf(fmaxf(0.f, sa[c] * v[j] + sd[c]));
      }
      *(uint4*)&sA[xr][xks] = pk.q;
    }
    { // stage B from W2: 128 rows x 32 k, two threads per row
      const float* wsrc = W2 + (size_t)wr * NCMID + k0 + wh;
      const float4 va = ((const float4*)wsrc)[0];
      const float4 vb = ((const float4*)wsrc)[1];
      const float4 vc = ((const float4*)wsrc)[2];
      const float4 vd = ((const float4*)wsrc)[3];
      PK8 pk;
      pk.u[0] = f2bf(va.x); pk.u[1] = f2bf(va.y); pk.u[2] = f2bf(va.z); pk.u[3] = f2bf(va.w);
      pk.u[4] = f2bf(vb.x); pk.u[5] = f2bf(vb.y); pk.u[6] = f2bf(vb.z); pk.u[7] = f2bf(vb.w);
      *(uint4*)&sB[wr][wh] = pk.q;
      pk.u[0] = f2bf(vc.x); pk.u[1] = f2bf(vc.y); pk.u[2] = f2bf(vc.z); pk.u[3] = f2bf(vc.w);
      pk.u[4] = f2bf(vd.x); pk.u[5] = f2bf(vd.y); pk.u[6] = f2bf(vd.z); pk.u[7] = f2bf(vd.w);
      *(uint4*)&sB[wr][wh + 8] = pk.q;
    }
    __syncthreads();
    const int fr = lane & 15;
    const int kq = (lane >> 4) * 8;
    const bf16x8 af = *(const bf16x8*)&sA[wave * 16 + fr][kq];
#pragma unroll
    for (int j = 0; j < 8; ++j) {
      const bf16x8 bfv = *(const bf16x8*)&sB[j * 16 + fr][kq];
      acc[j] = __builtin_amdgcn_mfma_f32_16x16x32_bf16(af, bfv, acc[j], 0, 0, 0);
    }
    __syncthreads();
  }

  const int col = lane & 15;
  const int r0 = (lane >> 4) * 4;
#pragma unroll
  for (int j = 0; j < 8; ++j) {
    const int ch = j * 16 + col;
    const float bb = bias2[ch];
#pragma unroll
    for (int q = 0; q < 4; ++q) {
      const int pt = ptBase + wave * 16 + r0 + q;
      out[(size_t)pt * NCOUT + ch] = acc[j][q] + bb;
    }
  }
}

// ---------------- final: in-place BN2-affine + ReLU on d_out ----------------
__global__ __launch_bounds__(256) void final_kernel(
    float* __restrict__ out, const float* __restrict__ a2, const float* __restrict__ d2)
{
  const int total4 = BNTOT * NCOUT / 4;   // 2,097,152 float4s
  for (int i = blockIdx.x * blockDim.x + threadIdx.x; i < total4;
       i += gridDim.x * blockDim.x) {
    float4 v = ((float4*)out)[i];
    const int c = (i & 31) * 4;           // 32 float4 per 128-ch row
    v.x = fmaxf(0.f, a2[c + 0] * v.x + d2[c + 0]);
    v.y = fmaxf(0.f, a2[c + 1] * v.y + d2[c + 1]);
    v.z = fmaxf(0.f, a2[c + 2] * v.z + d2[c + 2]);
    v.w = fmaxf(0.f, a2[c + 3] * v.w + d2[c + 3]);
    ((float4*)out)[i] = v;
  }
}

extern "C" void kernel_launch(void* const* d_in, const int* in_sizes, int n_in,
                              void* d_out, int out_size, void* d_ws, size_t ws_size,
                              hipStream_t stream) {
  const float* xyz1    = (const float*)d_in[0];
  const float* xyz2    = (const float*)d_in[1];
  const float* points1 = (const float*)d_in[2];
  const float* points2 = (const float*)d_in[3];
  const float* W1      = (const float*)d_in[4];
  const float* b1      = (const float*)d_in[5];
  const float* g1      = (const float*)d_in[6];
  const float* be1     = (const float*)d_in[7];
  const float* W2      = (const float*)d_in[8];
  const float* b2      = (const float*)d_in[9];
  const float* g2      = (const float*)d_in[10];
  const float* be2     = (const float*)d_in[11];
  float* out = (float*)d_out;

  char* ws = (char*)d_ws;
  const size_t interp_bytes = (size_t)BNTOT * ND2 * sizeof(float);    // 64 MB
  const size_t h1_bytes     = (size_t)BNTOT * NCMID * sizeof(float);  // 64 MB
  const size_t idx_bytes    = (size_t)BNTOT * 3 * sizeof(int);        // 768 KB
  float* interp = (float*)ws;
  float* h1     = (float*)(ws + interp_bytes);
  int*   nidx   = (int*)(ws + interp_bytes + h1_bytes);
  float* nwgt   = (float*)(ws + interp_bytes + h1_bytes + idx_bytes);
  float* stats  = (float*)(ws + interp_bytes + h1_bytes + 2 * idx_bytes);
  // stats layout: sum1[256] sq1[256] sum2[128] sq2[128] | a1[256] dd1[256] a2[128] dd2[128]
  float* sum1 = stats;
  float* sq1  = stats + 256;
  float* sum2 = stats + 512;
  float* sq2  = stats + 640;
  float* a1   = stats + 768;
  float* dd1  = stats + 1024;
  float* a2   = stats + 1280;
  float* dd2  = stats + 1408;

  // zero the accumulated sums (ws is poisoned, not re-zeroed between replays)
  hipMemsetAsync(stats, 0, 768 * sizeof(float), stream);

  knn_kernel<<<BNTOT / 64, 256, 0, stream>>>(xyz1, xyz2, nidx, nwgt);
  interp_kernel<<<BNTOT / 4, 256, 0, stream>>>(points2, nidx, nwgt, interp);
  gemm1_kernel<<<BNTOT / 64, 256, 0, stream>>>(points1, interp, W1, b1, h1);
  colsum_kernel<NCMID, 256><<<BNTOT / 256, NCMID, 0, stream>>>(h1, sum1, sq1);
  stats_kernel<NCMID><<<1, NCMID, 0, stream>>>(sum1, sq1, g1, be1, a1, dd1);
  gemm2_kernel<<<BNTOT / 64, 256, 0, stream>>>(h1, W2, b2, a1, dd1, out);
  colsum_kernel<NCOUT, 128><<<BNTOT / 128, NCOUT, 0, stream>>>(out, sum2, sq2);
  stats_kernel<NCOUT><<<1, NCOUT, 0, stream>>>(sum2, sq2, g2, be2, a2, dd2);
  final_kernel<<<2048, 256, 0, stream>>>(out, a2, dd2);
}

// Round 4
// 162.774 us; speedup vs baseline: 1.9628x; 1.3124x over previous
//
#include <hip/hip_runtime.h>
#include <hip/hip_bf16.h>

#define NB    16
#define NPT   4096
#define NSRC  1024
#define ND1   128
#define ND2   256
#define NCIN  384
#define NCMID 256
#define NCOUT 128
#define BNTOT (NB * NPT)   // 65536 points
#define BN_EPS 1e-5f

typedef float f32x4 __attribute__((ext_vector_type(4)));
typedef short bf16x8 __attribute__((ext_vector_type(8)));
typedef unsigned int uint;

union PK8 { unsigned short u[8]; uint4 q; };
union PK4 { unsigned short u[4]; uint2 q; };

static __device__ __forceinline__ unsigned short f2bf(float f) {
  __hip_bfloat16 h = __float2bfloat16(f);
  return __builtin_bit_cast(unsigned short, h);
}
static __device__ __forceinline__ float bf2f(unsigned short u) {
  return __builtin_bit_cast(float, (uint)u << 16);
}
// async global->LDS, 16B per lane; LDS dest must be wave-uniform chunk base.
static __device__ __forceinline__ void gl_lds16(const unsigned short* g, unsigned short* l) {
  __builtin_amdgcn_global_load_lds(
      (const __attribute__((address_space(1))) uint*)(const void*)g,
      (__attribute__((address_space(3))) uint*)(void*)l,
      16, 0, 0);
}

// total order: (d, idx) with ties -> lower index (matches lax.top_k)
static __device__ __forceinline__ bool prec(float da, int ia, float db, int ib) {
  return (da < db) || (da == db && ia < ib);
}

// ---------------- kNN (unchanged from round 3: passed, exact) ----------------
__global__ __launch_bounds__(256) void knn_kernel(
    const float* __restrict__ xyz1, const float* __restrict__ xyz2,
    int* __restrict__ nidx, float* __restrict__ nwgt)
{
  __shared__ float4 s2t[4 * 257];
  const int tid = threadIdx.x;
  const int b = blockIdx.x >> 6;
  {
    const float* src = xyz2 + (size_t)b * NSRC * 3 + tid * 12;
    const float4 l0 = ((const float4*)src)[0];
    const float4 l1 = ((const float4*)src)[1];
    const float4 l2 = ((const float4*)src)[2];
    const float xs[4] = {l0.x, l0.w, l1.z, l2.y};
    const float ys[4] = {l0.y, l1.x, l1.w, l2.z};
    const float zs[4] = {l0.z, l1.y, l2.x, l2.w};
    const int qq = tid >> 6;
    const int ibase = (tid & 63) * 4;
#pragma unroll
    for (int u = 0; u < 4; ++u) {
      const float c = xs[u] * xs[u] + ys[u] * ys[u] + zs[u] * zs[u];
      float4 v;
      v.x = -2.0f * xs[u]; v.y = -2.0f * ys[u]; v.z = -2.0f * zs[u]; v.w = c;
      s2t[qq * 257 + ibase + u] = v;
    }
  }
  __syncthreads();

  const int p = blockIdx.x * 64 + (tid >> 2);
  const int q = tid & 3;
  const float ax = xyz1[(size_t)p * 3 + 0];
  const float ay = xyz1[(size_t)p * 3 + 1];
  const float az = xyz1[(size_t)p * 3 + 2];
  const float a2 = ax * ax + ay * ay + az * az;
  const float4* slab = &s2t[q * 257];
  const int qbase = q * 256;

  const float INF = 3.4e38f;
  float ta0 = INF, ta1 = INF, ta2 = INF; int ja0 = 0, ja1 = 0, ja2 = 0;
  float tb0 = INF, tb1 = INF, tb2 = INF; int jb0 = 0, jb1 = 0, jb2 = 0;

#define INS3(t0, t1, t2, j0, j1, j2, d, idx)                                   \
  {                                                                            \
    const bool c0 = (d) < t0;                                                  \
    const float h0 = c0 ? t0 : (d); const int hj0 = c0 ? j0 : (idx);           \
    t0 = c0 ? (d) : t0;             j0 = c0 ? (idx) : j0;                      \
    const bool c1 = h0 < t1;                                                   \
    const float h1 = c1 ? t1 : h0;  const int hj1 = c1 ? j1 : hj0;             \
    t1 = c1 ? h0 : t1;              j1 = c1 ? hj0 : j1;                        \
    const bool c2 = h1 < t2;                                                   \
    t2 = c2 ? h1 : t2;              j2 = c2 ? hj1 : j2;                        \
  }

  for (int i = 0; i < 256; i += 2) {
    const float4 va = slab[i];
    float da = va.w + a2;
    da = fmaf(va.x, ax, da); da = fmaf(va.y, ay, da); da = fmaf(va.z, az, da);
    INS3(ta0, ta1, ta2, ja0, ja1, ja2, da, qbase + i);
    const float4 vb = slab[i + 1];
    float db = vb.w + a2;
    db = fmaf(vb.x, ax, db); db = fmaf(vb.y, ay, db); db = fmaf(vb.z, az, db);
    INS3(tb0, tb1, tb2, jb0, jb1, jb2, db, qbase + i + 1);
  }

#define MERGE3(d0, j0, d1, j1, d2, j2, e0, i0, e1, i1, e2, i2)                 \
  {                                                                            \
    const bool p0 = prec(d0, j0, e0, i0);                                      \
    const float l0d = p0 ? e0 : d0; const int l0j = p0 ? i0 : j0;              \
    const float r0d = p0 ? d0 : e0; const int r0j = p0 ? j0 : i0;              \
    const bool p1 = prec(d1, j1, e1, i1);                                      \
    const float w1d = p1 ? d1 : e1; const int w1j = p1 ? j1 : i1;              \
    const bool pr1 = prec(l0d, l0j, w1d, w1j);                                 \
    const float r1d = pr1 ? l0d : w1d; const int r1j = pr1 ? l0j : w1j;        \
    const float q1d = pr1 ? w1d : l0d; const int q1j = pr1 ? w1j : l0j;        \
    const bool p2 = prec(d2, j2, e2, i2);                                      \
    const float w2d = p2 ? d2 : e2; const int w2j = p2 ? j2 : i2;              \
    const bool pr2 = prec(q1d, q1j, w2d, w2j);                                 \
    const float r2d = pr2 ? q1d : w2d; const int r2j = pr2 ? q1j : w2j;        \
    d0 = r0d; j0 = r0j; d1 = r1d; j1 = r1j; d2 = r2d; j2 = r2j;                \
  }

  MERGE3(ta0, ja0, ta1, ja1, ta2, ja2, tb0, jb0, tb1, jb1, tb2, jb2);

#pragma unroll
  for (int m = 1; m <= 2; m <<= 1) {
    float e0 = __shfl_xor(ta0, m), e1 = __shfl_xor(ta1, m), e2 = __shfl_xor(ta2, m);
    int i0 = __shfl_xor(ja0, m), i1 = __shfl_xor(ja1, m), i2 = __shfl_xor(ja2, m);
    MERGE3(ta0, ja0, ta1, ja1, ta2, ja2, e0, i0, e1, i1, e2, i2);
  }

  if (q == 0) {
    float w0 = 1.f / (ta0 + 1e-8f), w1 = 1.f / (ta1 + 1e-8f), w2 = 1.f / (ta2 + 1e-8f);
    const float inv = 1.f / (w0 + w1 + w2);
    nidx[(size_t)p * 3 + 0] = ja0;
    nidx[(size_t)p * 3 + 1] = ja1;
    nidx[(size_t)p * 3 + 2] = ja2;
    nwgt[(size_t)p * 3 + 0] = w0 * inv;
    nwgt[(size_t)p * 3 + 1] = w1 * inv;
    nwgt[(size_t)p * 3 + 2] = w2 * inv;
  }
#undef INS3
#undef MERGE3
}

// ---------------- prep: W1,W2 fp32 -> bf16 ----------------
__global__ __launch_bounds__(256) void prep_w_kernel(
    const float* __restrict__ w1, const float* __restrict__ w2,
    unsigned short* __restrict__ w1b, unsigned short* __restrict__ w2b)
{
  const int i = blockIdx.x * 256 + threadIdx.x;   // 32768 float4 total
  const bool isW1 = i < 24576;                    // 98304/4
  const float4 v = isW1 ? ((const float4*)w1)[i] : ((const float4*)w2)[i - 24576];
  PK4 pk;
  pk.u[0] = f2bf(v.x); pk.u[1] = f2bf(v.y); pk.u[2] = f2bf(v.z); pk.u[3] = f2bf(v.w);
  if (isW1) ((uint2*)w1b)[i] = pk.q;
  else      ((uint2*)w2b)[i - 24576] = pk.q;
}

// ---------------- prep: points1 fp32 -> Xbf[:, 0:128] bf16 ----------------
__global__ __launch_bounds__(256) void prep_x_kernel(
    const float* __restrict__ points1, unsigned short* __restrict__ Xbf)
{
  const int t = blockIdx.x * 256 + threadIdx.x;   // 1M threads, 8 elems each
  const int pt = t >> 4;
  const int seg = (t & 15) * 8;
  const float4 va = ((const float4*)(points1 + (size_t)pt * ND1 + seg))[0];
  const float4 vb = ((const float4*)(points1 + (size_t)pt * ND1 + seg))[1];
  PK8 pk;
  pk.u[0] = f2bf(va.x); pk.u[1] = f2bf(va.y); pk.u[2] = f2bf(va.z); pk.u[3] = f2bf(va.w);
  pk.u[4] = f2bf(vb.x); pk.u[5] = f2bf(vb.y); pk.u[6] = f2bf(vb.z); pk.u[7] = f2bf(vb.w);
  *(uint4*)(Xbf + (size_t)pt * NCIN + seg) = pk.q;
}

// ---------------- interp: 3-NN weighted avg -> Xbf[:, 128:384] bf16 ----------------
__global__ __launch_bounds__(256) void interp_kernel(
    const float* __restrict__ points2, const int* __restrict__ nidx,
    const float* __restrict__ nwgt, unsigned short* __restrict__ Xbf)
{
  const int tid = threadIdx.x;
  const int pt = blockIdx.x * 8 + (tid >> 5);     // 8 points per block
  const int c8 = (tid & 31) * 8;                  // 8-channel segment
  const int b = pt >> 12;
  const float* p2 = points2 + (size_t)b * NSRC * ND2;
  const int j0 = nidx[pt * 3 + 0], j1 = nidx[pt * 3 + 1], j2 = nidx[pt * 3 + 2];
  const float w0 = nwgt[pt * 3 + 0], w1 = nwgt[pt * 3 + 1], w2 = nwgt[pt * 3 + 2];
  const float4* r0 = (const float4*)(p2 + (size_t)j0 * ND2 + c8);
  const float4* r1 = (const float4*)(p2 + (size_t)j1 * ND2 + c8);
  const float4* r2 = (const float4*)(p2 + (size_t)j2 * ND2 + c8);
  PK8 pk;
#pragma unroll
  for (int h = 0; h < 2; ++h) {
    const float4 va = r0[h], vb = r1[h], vc = r2[h];
    pk.u[h * 4 + 0] = f2bf(w0 * va.x + w1 * vb.x + w2 * vc.x);
    pk.u[h * 4 + 1] = f2bf(w0 * va.y + w1 * vb.y + w2 * vc.y);
    pk.u[h * 4 + 2] = f2bf(w0 * va.z + w1 * vb.z + w2 * vc.z);
    pk.u[h * 4 + 3] = f2bf(w0 * va.w + w1 * vb.w + w2 * vc.w);
  }
  *(uint4*)(Xbf + (size_t)pt * NCIN + ND1 + c8) = pk.q;
}

// ---------------- GEMM1: h1bf[pt][c] = bf16( b1[c] + sum_k Xbf[pt][k]*W1bf[c][k] )
// M=65536, N=256, K=384. BM=128, BK=32, 4 waves (each 32 pts x 256 ch).
// LDS: linear rows of 64B, k-slot XOR swizzle c16 ^= (row>>1)&3 (2-way = free).
// Staged via global_load_lds(16B), double-buffered, one barrier per kt.
__global__ __launch_bounds__(256, 2) void gemm1_kernel(
    const unsigned short* __restrict__ Xbf, const unsigned short* __restrict__ W1bf,
    const float* __restrict__ bias1, unsigned short* __restrict__ h1bf)
{
  __shared__ unsigned short sA[2][128][32];   // 16 KB
  __shared__ unsigned short sB[2][256][32];   // 32 KB
  const int tid = threadIdx.x;
  const int lane = tid & 63;
  const int wave = tid >> 6;
  const int ptBase = blockIdx.x * 128;

  f32x4 acc[2][16];
#pragma unroll
  for (int m = 0; m < 2; ++m)
#pragma unroll
    for (int j = 0; j < 16; ++j)
#pragma unroll
      for (int q = 0; q < 4; ++q) acc[m][j][q] = 0.0f;

  const int fr = lane & 15;
  const int cs = lane >> 4;                       // k-slot 0..3 (kq = cs*8)
  const int rdsh = ((cs ^ ((fr >> 1) & 3)) << 3); // swizzled read offset (shorts)

  auto stage = [&](int buf, int kt) {
    const int k0 = kt * 32;
#pragma unroll
    for (int c = 0; c < 2; ++c) {                 // A: 512 slots of 16B
      const int s = c * 256 + wave * 64 + lane;
      const int row = s >> 2, c16 = s & 3;
      const int ks = c16 ^ ((row >> 1) & 3);
      gl_lds16(Xbf + (size_t)(ptBase + row) * NCIN + k0 + ks * 8,
               &sA[buf][0][0] + (c * 256 + wave * 64) * 8);
    }
#pragma unroll
    for (int c = 0; c < 4; ++c) {                 // B: 1024 slots of 16B
      const int s = c * 256 + wave * 64 + lane;
      const int row = s >> 2, c16 = s & 3;
      const int ks = c16 ^ ((row >> 1) & 3);
      gl_lds16(W1bf + (size_t)row * NCIN + k0 + ks * 8,
               &sB[buf][0][0] + (c * 256 + wave * 64) * 8);
    }
  };

  stage(0, 0);
  __syncthreads();
  int cur = 0;
  for (int kt = 0; kt < 12; ++kt) {
    if (kt < 11) stage(cur ^ 1, kt + 1);
    const bf16x8 a0 = *(const bf16x8*)&sA[cur][wave * 32 + fr][rdsh];
    const bf16x8 a1 = *(const bf16x8*)&sA[cur][wave * 32 + 16 + fr][rdsh];
#pragma unroll
    for (int j = 0; j < 16; ++j) {
      const bf16x8 b = *(const bf16x8*)&sB[cur][j * 16 + fr][rdsh];
      acc[0][j] = __builtin_amdgcn_mfma_f32_16x16x32_bf16(a0, b, acc[0][j], 0, 0, 0);
      acc[1][j] = __builtin_amdgcn_mfma_f32_16x16x32_bf16(a1, b, acc[1][j], 0, 0, 0);
    }
    __syncthreads();
    cur ^= 1;
  }

  // D layout: col=lane&15 -> channel, row=(lane>>4)*4+q -> point [m89/m91]
  const int col = fr;
  const int r0 = cs * 4;
#pragma unroll
  for (int j = 0; j < 16; ++j) {
    const int ch = j * 16 + col;
    const float bb = bias1[ch];
#pragma unroll
    for (int m = 0; m < 2; ++m)
#pragma unroll
      for (int q = 0; q < 4; ++q) {
        const int pt = ptBase + wave * 32 + m * 16 + r0 + q;
        h1bf[(size_t)pt * NCMID + ch] = f2bf(acc[m][j][q] + bb);
      }
  }
}

// ---------------- per-channel column sums over bf16 matrix ----------------
template <int C, int R>
__global__ void colsum_bf_kernel(const unsigned short* __restrict__ x,
                                 float* __restrict__ sum, float* __restrict__ sumsq)
{
  const int t = threadIdx.x;
  const size_t r0 = (size_t)blockIdx.x * R;
  float s = 0.f, s2 = 0.f;
  for (int r = 0; r < R; ++r) {
    const float v = bf2f(x[(r0 + r) * C + t]);
    s += v; s2 += v * v;
  }
  atomicAdd(&sum[t], s);
  atomicAdd(&sumsq[t], s2);
}

// ---------------- per-channel column sums over fp32 matrix ----------------
template <int C, int R>
__global__ void colsum_kernel(const float* __restrict__ x,
                              float* __restrict__ sum, float* __restrict__ sumsq)
{
  const int t = threadIdx.x;
  const size_t r0 = (size_t)blockIdx.x * R;
  float s = 0.f, s2 = 0.f;
  for (int r = 0; r < R; ++r) {
    const float v = x[(r0 + r) * C + t];
    s += v; s2 += v * v;
  }
  atomicAdd(&sum[t], s);
  atomicAdd(&sumsq[t], s2);
}

// ---------------- fold BN into per-channel affine: y = a*x + d ----------------
template <int C>
__global__ void stats_kernel(const float* __restrict__ sum, const float* __restrict__ sumsq,
                             const float* __restrict__ g, const float* __restrict__ be,
                             float* __restrict__ a, float* __restrict__ d)
{
  const int c = threadIdx.x;
  const float mean = sum[c] * (1.0f / BNTOT);
  const float var = sumsq[c] * (1.0f / BNTOT) - mean * mean;
  const float inv = rsqrtf(var + BN_EPS);
  const float ac = g[c] * inv;
  a[c] = ac;
  d[c] = be[c] - mean * ac;
}

// ---------------- GEMM2: out[pt][c] = b2[c] + sum_k relu(a1[k]*h1[k]+d1[k])*W2[c][k]
// M=65536, N=128, K=256. BM=128, BK=32. A reg-staged (affine+relu fused),
// B via global_load_lds. Same swizzle as gemm1.
__global__ __launch_bounds__(256, 2) void gemm2_kernel(
    const unsigned short* __restrict__ h1bf, const unsigned short* __restrict__ W2bf,
    const float* __restrict__ bias2, const float* __restrict__ aff_a,
    const float* __restrict__ aff_d, float* __restrict__ out)
{
  __shared__ unsigned short sA[2][128][32];   // 16 KB
  __shared__ unsigned short sB[2][128][32];   // 16 KB
  __shared__ float sa[NCMID], sd[NCMID];
  const int tid = threadIdx.x;
  const int lane = tid & 63;
  const int wave = tid >> 6;
  const int ptBase = blockIdx.x * 128;
  sa[tid] = aff_a[tid];
  sd[tid] = aff_d[tid];

  f32x4 acc[2][8];
#pragma unroll
  for (int m = 0; m < 2; ++m)
#pragma unroll
    for (int j = 0; j < 8; ++j)
#pragma unroll
      for (int q = 0; q < 4; ++q) acc[m][j][q] = 0.0f;

  const int fr = lane & 15;
  const int cs = lane >> 4;
  const int rdsh = ((cs ^ ((fr >> 1) & 3)) << 3);

  auto stageB = [&](int buf, int kt) {
    const int k0 = kt * 32;
#pragma unroll
    for (int c = 0; c < 2; ++c) {                 // B: 512 slots of 16B
      const int s = c * 256 + wave * 64 + lane;
      const int row = s >> 2, c16 = s & 3;
      const int ks = c16 ^ ((row >> 1) & 3);
      gl_lds16(W2bf + (size_t)row * NCMID + k0 + ks * 8,
               &sB[buf][0][0] + (c * 256 + wave * 64) * 8);
    }
  };
  auto stageA = [&](int buf, int kt) {            // reg-staged, affine+relu fused
    const int k0 = kt * 32;
#pragma unroll
    for (int c = 0; c < 2; ++c) {
      const int s = c * 256 + tid;
      const int row = s >> 2, c16 = s & 3;
      const int ks = c16 ^ ((row >> 1) & 3);
      const int k = k0 + ks * 8;
      PK8 v;
      v.q = *(const uint4*)(h1bf + (size_t)(ptBase + row) * NCMID + k);
      PK8 pk;
#pragma unroll
      for (int j = 0; j < 8; ++j)
        pk.u[j] = f2bf(fmaxf(0.f, sa[k + j] * bf2f(v.u[j]) + sd[k + j]));
      *(uint4*)(&sA[buf][0][0] + s * 8) = pk.q;
    }
  };

  stageB(0, 0);
  __syncthreads();      // also covers sa/sd init before stageA reads them
  stageA(0, 0);
  __syncthreads();
  int cur = 0;
  for (int kt = 0; kt < 8; ++kt) {
    if (kt < 7) { stageB(cur ^ 1, kt + 1); stageA(cur ^ 1, kt + 1); }
    const bf16x8 a0 = *(const bf16x8*)&sA[cur][wave * 32 + fr][rdsh];
    const bf16x8 a1 = *(const bf16x8*)&sA[cur][wave * 32 + 16 + fr][rdsh];
#pragma unroll
    for (int j = 0; j < 8; ++j) {
      const bf16x8 b = *(const bf16x8*)&sB[cur][j * 16 + fr][rdsh];
      acc[0][j] = __builtin_amdgcn_mfma_f32_16x16x32_bf16(a0, b, acc[0][j], 0, 0, 0);
      acc[1][j] = __builtin_amdgcn_mfma_f32_16x16x32_bf16(a1, b, acc[1][j], 0, 0, 0);
    }
    __syncthreads();
    cur ^= 1;
  }

  const int col = fr;
  const int r0 = cs * 4;
#pragma unroll
  for (int j = 0; j < 8; ++j) {
    const int ch = j * 16 + col;
    const float bb = bias2[ch];
#pragma unroll
    for (int m = 0; m < 2; ++m)
#pragma unroll
      for (int q = 0; q < 4; ++q) {
        const int pt = ptBase + wave * 32 + m * 16 + r0 + q;
        out[(size_t)pt * NCOUT + ch] = acc[m][j][q] + bb;
      }
  }
}

// ---------------- final: in-place BN2-affine + ReLU on d_out ----------------
__global__ __launch_bounds__(256) void final_kernel(
    float* __restrict__ out, const float* __restrict__ a2, const float* __restrict__ d2)
{
  const int total4 = BNTOT * NCOUT / 4;
  for (int i = blockIdx.x * blockDim.x + threadIdx.x; i < total4;
       i += gridDim.x * blockDim.x) {
    float4 v = ((float4*)out)[i];
    const int c = (i & 31) * 4;
    v.x = fmaxf(0.f, a2[c + 0] * v.x + d2[c + 0]);
    v.y = fmaxf(0.f, a2[c + 1] * v.y + d2[c + 1]);
    v.z = fmaxf(0.f, a2[c + 2] * v.z + d2[c + 2]);
    v.w = fmaxf(0.f, a2[c + 3] * v.w + d2[c + 3]);
    ((float4*)out)[i] = v;
  }
}

extern "C" void kernel_launch(void* const* d_in, const int* in_sizes, int n_in,
                              void* d_out, int out_size, void* d_ws, size_t ws_size,
                              hipStream_t stream) {
  const float* xyz1    = (const float*)d_in[0];
  const float* xyz2    = (const float*)d_in[1];
  const float* points1 = (const float*)d_in[2];
  const float* points2 = (const float*)d_in[3];
  const float* W1      = (const float*)d_in[4];
  const float* b1      = (const float*)d_in[5];
  const float* g1      = (const float*)d_in[6];
  const float* be1     = (const float*)d_in[7];
  const float* W2      = (const float*)d_in[8];
  const float* b2      = (const float*)d_in[9];
  const float* g2      = (const float*)d_in[10];
  const float* be2     = (const float*)d_in[11];
  float* out = (float*)d_out;

  char* ws = (char*)d_ws;
  const size_t xbf_bytes  = (size_t)BNTOT * NCIN * 2;     // 48 MB
  const size_t h1_bytes   = (size_t)BNTOT * NCMID * 2;    // 32 MB
  const size_t w1b_bytes  = (size_t)NCMID * NCIN * 2;     // 192 KB
  const size_t w2b_bytes  = (size_t)NCOUT * NCMID * 2;    // 64 KB
  const size_t idx_bytes  = (size_t)BNTOT * 3 * 4;        // 768 KB
  unsigned short* Xbf  = (unsigned short*)ws;
  unsigned short* h1bf = (unsigned short*)(ws + xbf_bytes);
  unsigned short* W1bf = (unsigned short*)(ws + xbf_bytes + h1_bytes);
  unsigned short* W2bf = (unsigned short*)(ws + xbf_bytes + h1_bytes + w1b_bytes);
  int*   nidx = (int*)(ws + xbf_bytes + h1_bytes + w1b_bytes + w2b_bytes);
  float* nwgt = (float*)(ws + xbf_bytes + h1_bytes + w1b_bytes + w2b_bytes + idx_bytes);
  float* stats = (float*)(ws + xbf_bytes + h1_bytes + w1b_bytes + w2b_bytes + 2 * idx_bytes);
  float* sum1 = stats;
  float* sq1  = stats + 256;
  float* sum2 = stats + 512;
  float* sq2  = stats + 640;
  float* a1   = stats + 768;
  float* dd1  = stats + 1024;
  float* a2   = stats + 1280;
  float* dd2  = stats + 1408;

  hipMemsetAsync(stats, 0, 768 * sizeof(float), stream);

  prep_w_kernel<<<128, 256, 0, stream>>>(W1, W2, W1bf, W2bf);
  prep_x_kernel<<<BNTOT * (ND1 / 8) / 256, 256, 0, stream>>>(points1, Xbf);
  knn_kernel<<<BNTOT / 64, 256, 0, stream>>>(xyz1, xyz2, nidx, nwgt);
  interp_kernel<<<BNTOT / 8, 256, 0, stream>>>(points2, nidx, nwgt, Xbf);
  gemm1_kernel<<<BNTOT / 128, 256, 0, stream>>>(Xbf, W1bf, b1, h1bf);
  colsum_bf_kernel<NCMID, 256><<<BNTOT / 256, NCMID, 0, stream>>>(h1bf, sum1, sq1);
  stats_kernel<NCMID><<<1, NCMID, 0, stream>>>(sum1, sq1, g1, be1, a1, dd1);
  gemm2_kernel<<<BNTOT / 128, 256, 0, stream>>>(h1bf, W2bf, b2, a1, dd1, out);
  colsum_kernel<NCOUT, 128><<<BNTOT / 128, NCOUT, 0, stream>>>(out, sum2, sq2);
  stats_kernel<NCOUT><<<1, NCOUT, 0, stream>>>(sum2, sq2, g2, be2, a2, dd2);
  final_kernel<<<2048, 256, 0, stream>>>(out, a2, dd2);
}

// Round 5
// 150.494 us; speedup vs baseline: 2.1230x; 1.0816x over previous
//
#include <hip/hip_runtime.h>
#include <hip/hip_bf16.h>

#define NB    16
#define NPT   4096
#define NSRC  1024
#define ND1   128
#define ND2   256
#define NCIN  384
#define NCMID 256
#define NCOUT 128
#define BNTOT (NB * NPT)   // 65536 points
#define BN_EPS 1e-5f

typedef float f32x4 __attribute__((ext_vector_type(4)));
typedef short bf16x8 __attribute__((ext_vector_type(8)));
typedef unsigned int uint;

union PK8 { unsigned short u[8]; uint4 q; };
union PK4 { unsigned short u[4]; uint2 q; };

static __device__ __forceinline__ unsigned short f2bf(float f) {
  __hip_bfloat16 h = __float2bfloat16(f);
  return __builtin_bit_cast(unsigned short, h);
}
static __device__ __forceinline__ float bf2f(unsigned short u) {
  return __builtin_bit_cast(float, (uint)u << 16);
}
static __device__ __forceinline__ void gl_lds16(const unsigned short* g, unsigned short* l) {
  __builtin_amdgcn_global_load_lds(
      (const __attribute__((address_space(1))) uint*)(const void*)g,
      (__attribute__((address_space(3))) uint*)(void*)l,
      16, 0, 0);
}

#if __has_builtin(__builtin_amdgcn_fmed3f)
#define MED3F(a, b, c) __builtin_amdgcn_fmed3f((a), (b), (c))
#else
// valid because callers guarantee a <= b: median == clamp(c, a, b)
#define MED3F(a, b, c) fmaxf((a), fminf((b), (c)))
#endif

// total order: (d, idx) with ties -> lower index (matches lax.top_k)
static __device__ __forceinline__ bool prec(float da, int ia, float db, int ib) {
  return (da < db) || (da == db && ia < ib);
}

// shallow branchless top-3 insert: compares vs OLD state (dep depth 2).
// tie semantics: d == t_k keeps incumbent (lower scan index). Verified cases:
//  d<t0: [d,t0,t1]; t0<=d<t1: [t0,d,t1]; t1<=d<t2: [t0,t1,d]; d>=t2: unchanged.
#define INSV(t0, t1, t2, j0, j1, j2, d, idx)                                   \
  {                                                                            \
    const bool c0 = (d) < t0;                                                  \
    const bool c1 = (d) < t1;                                                  \
    const bool c2 = (d) < t2;                                                  \
    const float m1 = MED3F(t0, t1, (d));                                       \
    const float m2 = fminf(t2, fmaxf(t1, (d)));                                \
    t0 = fminf(t0, (d));                                                       \
    j2 = c2 ? (c1 ? j1 : (idx)) : j2;                                          \
    j1 = c1 ? (c0 ? j0 : (idx)) : j1;                                          \
    j0 = c0 ? (idx) : j0;                                                      \
    t1 = m1; t2 = m2;                                                          \
  }

#define MERGE3(d0, j0, d1, j1, d2, j2, e0, i0, e1, i1, e2, i2)                 \
  {                                                                            \
    const bool p0 = prec(d0, j0, e0, i0);                                      \
    const float l0d = p0 ? e0 : d0; const int l0j = p0 ? i0 : j0;              \
    const float r0d = p0 ? d0 : e0; const int r0j = p0 ? j0 : i0;              \
    const bool p1 = prec(d1, j1, e1, i1);                                      \
    const float w1d = p1 ? d1 : e1; const int w1j = p1 ? j1 : i1;              \
    const bool pr1 = prec(l0d, l0j, w1d, w1j);                                 \
    const float r1d = pr1 ? l0d : w1d; const int r1j = pr1 ? l0j : w1j;        \
    const float q1d = pr1 ? w1d : l0d; const int q1j = pr1 ? w1j : l0j;        \
    const bool p2 = prec(d2, j2, e2, i2);                                      \
    const float w2d = p2 ? d2 : e2; const int w2j = p2 ? j2 : i2;              \
    const bool pr2 = prec(q1d, q1j, w2d, w2j);                                 \
    const float r2d = pr2 ? q1d : w2d; const int r2j = pr2 ? q1j : w2j;        \
    d0 = r0d; j0 = r0j; d1 = r1d; j1 = r1j; d2 = r2d; j2 = r2j;                \
  }

// ---------------- fused front: kNN + 3-NN interp + points1 cast -> Xbf ----------------
// 2048 blocks x 32 points. 8 lanes per point scan 128 sources each.
__global__ __launch_bounds__(256) void front_kernel(
    const float* __restrict__ xyz1, const float* __restrict__ xyz2,
    const float* __restrict__ points1, const float* __restrict__ points2,
    unsigned short* __restrict__ Xbf)
{
  __shared__ float4 s2t[8 * 129];    // 8 slabs of 128 transformed sources (+pad)
  __shared__ int   sj[32][3];
  __shared__ float sw[32][3];
  const int tid = threadIdx.x;
  const int ptBase = blockIdx.x * 32;
  const int b = ptBase >> 12;        // batch (32 | 4096, no straddle)

  { // stage + transform xyz2: thread t covers sources 4t..4t+3
    const float* src = xyz2 + (size_t)b * NSRC * 3 + tid * 12;
    const float4 l0 = ((const float4*)src)[0];
    const float4 l1 = ((const float4*)src)[1];
    const float4 l2 = ((const float4*)src)[2];
    const float xs[4] = {l0.x, l0.w, l1.z, l2.y};
    const float ys[4] = {l0.y, l1.x, l1.w, l2.z};
    const float zs[4] = {l0.z, l1.y, l2.x, l2.w};
#pragma unroll
    for (int u = 0; u < 4; ++u) {
      const int s = tid * 4 + u;
      const float c = xs[u] * xs[u] + ys[u] * ys[u] + zs[u] * zs[u];
      float4 v;
      v.x = -2.0f * xs[u]; v.y = -2.0f * ys[u]; v.z = -2.0f * zs[u]; v.w = c;
      s2t[(s >> 7) * 129 + (s & 127)] = v;
    }
  }

  const int ptl = tid >> 3;                 // 0..31 local point
  const int q = tid & 7;                    // source octant
  const int p = ptBase + ptl;

  { // phase 3 (independent of knn): points1 -> Xbf[:, 0:128]
    const int c16 = q * 16;
    const float* src = points1 + (size_t)p * ND1 + c16;
    const float4 v0 = ((const float4*)src)[0];
    const float4 v1 = ((const float4*)src)[1];
    const float4 v2 = ((const float4*)src)[2];
    const float4 v3 = ((const float4*)src)[3];
    PK8 pk;
    pk.u[0] = f2bf(v0.x); pk.u[1] = f2bf(v0.y); pk.u[2] = f2bf(v0.z); pk.u[3] = f2bf(v0.w);
    pk.u[4] = f2bf(v1.x); pk.u[5] = f2bf(v1.y); pk.u[6] = f2bf(v1.z); pk.u[7] = f2bf(v1.w);
    *(uint4*)(Xbf + (size_t)p * NCIN + c16) = pk.q;
    pk.u[0] = f2bf(v2.x); pk.u[1] = f2bf(v2.y); pk.u[2] = f2bf(v2.z); pk.u[3] = f2bf(v2.w);
    pk.u[4] = f2bf(v3.x); pk.u[5] = f2bf(v3.y); pk.u[6] = f2bf(v3.z); pk.u[7] = f2bf(v3.w);
    *(uint4*)(Xbf + (size_t)p * NCIN + c16 + 8) = pk.q;
  }
  __syncthreads();

  // ---- kNN scan: 128 candidates per lane, 2 interleaved shallow chains ----
  const float ax = xyz1[(size_t)p * 3 + 0];
  const float ay = xyz1[(size_t)p * 3 + 1];
  const float az = xyz1[(size_t)p * 3 + 2];
  const float a2 = ax * ax + ay * ay + az * az;
  const float4* slab = &s2t[q * 129];
  const int qbase = q * 128;

  const float INF = 3.4e38f;
  float ta0 = INF, ta1 = INF, ta2 = INF; int ja0 = 0, ja1 = 0, ja2 = 0;
  float tb0 = INF, tb1 = INF, tb2 = INF; int jb0 = 0, jb1 = 0, jb2 = 0;

  for (int i = 0; i < 128; i += 2) {
    const float4 va = slab[i];
    float da = va.w + a2;
    da = fmaf(va.x, ax, da); da = fmaf(va.y, ay, da); da = fmaf(va.z, az, da);
    INSV(ta0, ta1, ta2, ja0, ja1, ja2, da, qbase + i);
    const float4 vb = slab[i + 1];
    float db = vb.w + a2;
    db = fmaf(vb.x, ax, db); db = fmaf(vb.y, ay, db); db = fmaf(vb.z, az, db);
    INSV(tb0, tb1, tb2, jb0, jb1, jb2, db, qbase + i + 1);
  }
  MERGE3(ta0, ja0, ta1, ja1, ta2, ja2, tb0, jb0, tb1, jb1, tb2, jb2);

#pragma unroll
  for (int m = 1; m <= 4; m <<= 1) {
    float e0 = __shfl_xor(ta0, m), e1 = __shfl_xor(ta1, m), e2 = __shfl_xor(ta2, m);
    int i0 = __shfl_xor(ja0, m), i1 = __shfl_xor(ja1, m), i2 = __shfl_xor(ja2, m);
    MERGE3(ta0, ja0, ta1, ja1, ta2, ja2, e0, i0, e1, i1, e2, i2);
  }

  if (q == 0) {
    float w0 = 1.f / (ta0 + 1e-8f), w1 = 1.f / (ta1 + 1e-8f), w2 = 1.f / (ta2 + 1e-8f);
    const float inv = 1.f / (w0 + w1 + w2);
    sj[ptl][0] = ja0; sj[ptl][1] = ja1; sj[ptl][2] = ja2;
    sw[ptl][0] = w0 * inv; sw[ptl][1] = w1 * inv; sw[ptl][2] = w2 * inv;
  }
  __syncthreads();

  { // phase 2: gather + weighted avg -> Xbf[:, 128:384]
    const int j0 = sj[ptl][0], j1 = sj[ptl][1], j2 = sj[ptl][2];
    const float w0 = sw[ptl][0], w1 = sw[ptl][1], w2 = sw[ptl][2];
    const float* p2 = points2 + (size_t)b * NSRC * ND2;
    const int c32 = q * 32;
    const float4* r0 = (const float4*)(p2 + (size_t)j0 * ND2 + c32);
    const float4* r1 = (const float4*)(p2 + (size_t)j1 * ND2 + c32);
    const float4* r2 = (const float4*)(p2 + (size_t)j2 * ND2 + c32);
#pragma unroll
    for (int g = 0; g < 4; ++g) {           // 4 groups of 8 channels
      PK8 pk;
#pragma unroll
      for (int h = 0; h < 2; ++h) {
        const float4 va = r0[g * 2 + h], vb = r1[g * 2 + h], vc = r2[g * 2 + h];
        pk.u[h * 4 + 0] = f2bf(w0 * va.x + w1 * vb.x + w2 * vc.x);
        pk.u[h * 4 + 1] = f2bf(w0 * va.y + w1 * vb.y + w2 * vc.y);
        pk.u[h * 4 + 2] = f2bf(w0 * va.z + w1 * vb.z + w2 * vc.z);
        pk.u[h * 4 + 3] = f2bf(w0 * va.w + w1 * vb.w + w2 * vc.w);
      }
      *(uint4*)(Xbf + (size_t)p * NCIN + ND1 + c32 + g * 8) = pk.q;
    }
  }
}

// ---------------- prep: W1,W2 fp32 -> bf16 ----------------
__global__ __launch_bounds__(256) void prep_w_kernel(
    const float* __restrict__ w1, const float* __restrict__ w2,
    unsigned short* __restrict__ w1b, unsigned short* __restrict__ w2b)
{
  const int i = blockIdx.x * 256 + threadIdx.x;
  const bool isW1 = i < 24576;
  const float4 v = isW1 ? ((const float4*)w1)[i] : ((const float4*)w2)[i - 24576];
  PK4 pk;
  pk.u[0] = f2bf(v.x); pk.u[1] = f2bf(v.y); pk.u[2] = f2bf(v.z); pk.u[3] = f2bf(v.w);
  if (isW1) ((uint2*)w1b)[i] = pk.q;
  else      ((uint2*)w2b)[i - 24576] = pk.q;
}

// ---------------- GEMM1 (+fused BN1 column sums) ----------------
__global__ __launch_bounds__(256, 2) void gemm1_kernel(
    const unsigned short* __restrict__ Xbf, const unsigned short* __restrict__ W1bf,
    const float* __restrict__ bias1, unsigned short* __restrict__ h1bf,
    float* __restrict__ sum1, float* __restrict__ sq1)
{
  __shared__ unsigned short sA[2][128][32];   // 16 KB
  __shared__ unsigned short sB[2][256][32];   // 32 KB
  const int tid = threadIdx.x;
  const int lane = tid & 63;
  const int wave = tid >> 6;
  const int ptBase = blockIdx.x * 128;

  f32x4 acc[2][16];
#pragma unroll
  for (int m = 0; m < 2; ++m)
#pragma unroll
    for (int j = 0; j < 16; ++j)
#pragma unroll
      for (int q = 0; q < 4; ++q) acc[m][j][q] = 0.0f;

  const int fr = lane & 15;
  const int cs = lane >> 4;
  const int rdsh = ((cs ^ ((fr >> 1) & 3)) << 3);

  auto stage = [&](int buf, int kt) {
    const int k0 = kt * 32;
#pragma unroll
    for (int c = 0; c < 2; ++c) {
      const int s = c * 256 + wave * 64 + lane;
      const int row = s >> 2, c16 = s & 3;
      const int ks = c16 ^ ((row >> 1) & 3);
      gl_lds16(Xbf + (size_t)(ptBase + row) * NCIN + k0 + ks * 8,
               &sA[buf][0][0] + (c * 256 + wave * 64) * 8);
    }
#pragma unroll
    for (int c = 0; c < 4; ++c) {
      const int s = c * 256 + wave * 64 + lane;
      const int row = s >> 2, c16 = s & 3;
      const int ks = c16 ^ ((row >> 1) & 3);
      gl_lds16(W1bf + (size_t)row * NCIN + k0 + ks * 8,
               &sB[buf][0][0] + (c * 256 + wave * 64) * 8);
    }
  };

  stage(0, 0);
  __syncthreads();
  int cur = 0;
  for (int kt = 0; kt < 12; ++kt) {
    if (kt < 11) stage(cur ^ 1, kt + 1);
    const bf16x8 a0 = *(const bf16x8*)&sA[cur][wave * 32 + fr][rdsh];
    const bf16x8 a1 = *(const bf16x8*)&sA[cur][wave * 32 + 16 + fr][rdsh];
#pragma unroll
    for (int j = 0; j < 16; ++j) {
      const bf16x8 b = *(const bf16x8*)&sB[cur][j * 16 + fr][rdsh];
      acc[0][j] = __builtin_amdgcn_mfma_f32_16x16x32_bf16(a0, b, acc[0][j], 0, 0, 0);
      acc[1][j] = __builtin_amdgcn_mfma_f32_16x16x32_bf16(a1, b, acc[1][j], 0, 0, 0);
    }
    __syncthreads();
    cur ^= 1;
  }

  // epilogue: store h1 bf16 + per-channel partial sums (BN1 stats)
  float* redS = (float*)&sA[0][0][0];         // overlay (all LDS reads done)
  float* redQ = redS + 1024;
  const int col = fr;
  const int r0 = cs * 4;
#pragma unroll
  for (int j = 0; j < 16; ++j) {
    const int ch = j * 16 + col;
    const float bb = bias1[ch];
    float s = 0.f, s2 = 0.f;
#pragma unroll
    for (int m = 0; m < 2; ++m)
#pragma unroll
      for (int q = 0; q < 4; ++q) {
        const int pt = ptBase + wave * 32 + m * 16 + r0 + q;
        const float v = acc[m][j][q] + bb;
        h1bf[(size_t)pt * NCMID + ch] = f2bf(v);
        s += v; s2 += v * v;
      }
    s += __shfl_xor(s, 16);  s2 += __shfl_xor(s2, 16);
    s += __shfl_xor(s, 32);  s2 += __shfl_xor(s2, 32);
    if (cs == 0) { redS[wave * 256 + fr * 16 + j] = s; redQ[wave * 256 + fr * 16 + j] = s2; }
  }
  __syncthreads();
  {
    const int ch = tid;
    const int f = ch & 15, j = ch >> 4;
    float s = 0.f, s2 = 0.f;
#pragma unroll
    for (int w = 0; w < 4; ++w) {
      s  += redS[w * 256 + f * 16 + j];
      s2 += redQ[w * 256 + f * 16 + j];
    }
    atomicAdd(&sum1[ch], s);
    atomicAdd(&sq1[ch], s2);
  }
}

// ---------------- fold BN into per-channel affine: y = a*x + d ----------------
template <int C>
__global__ void stats_kernel(const float* __restrict__ sum, const float* __restrict__ sumsq,
                             const float* __restrict__ g, const float* __restrict__ be,
                             float* __restrict__ a, float* __restrict__ d)
{
  const int c = threadIdx.x;
  const float mean = sum[c] * (1.0f / BNTOT);
  const float var = sumsq[c] * (1.0f / BNTOT) - mean * mean;
  const float inv = rsqrtf(var + BN_EPS);
  const float ac = g[c] * inv;
  a[c] = ac;
  d[c] = be[c] - mean * ac;
}

// ---------------- GEMM2 (+fused BN2 column sums, bf16 out) ----------------
__global__ __launch_bounds__(256, 2) void gemm2_kernel(
    const unsigned short* __restrict__ h1bf, const unsigned short* __restrict__ W2bf,
    const float* __restrict__ bias2, const float* __restrict__ aff_a,
    const float* __restrict__ aff_d, unsigned short* __restrict__ h2bf,
    float* __restrict__ sum2, float* __restrict__ sq2)
{
  __shared__ unsigned short sA[2][128][32];
  __shared__ unsigned short sB[2][128][32];
  __shared__ float sa[NCMID], sd[NCMID];
  const int tid = threadIdx.x;
  const int lane = tid & 63;
  const int wave = tid >> 6;
  const int ptBase = blockIdx.x * 128;
  sa[tid] = aff_a[tid];
  sd[tid] = aff_d[tid];

  f32x4 acc[2][8];
#pragma unroll
  for (int m = 0; m < 2; ++m)
#pragma unroll
    for (int j = 0; j < 8; ++j)
#pragma unroll
      for (int q = 0; q < 4; ++q) acc[m][j][q] = 0.0f;

  const int fr = lane & 15;
  const int cs = lane >> 4;
  const int rdsh = ((cs ^ ((fr >> 1) & 3)) << 3);

  auto stageB = [&](int buf, int kt) {
    const int k0 = kt * 32;
#pragma unroll
    for (int c = 0; c < 2; ++c) {
      const int s = c * 256 + wave * 64 + lane;
      const int row = s >> 2, c16 = s & 3;
      const int ks = c16 ^ ((row >> 1) & 3);
      gl_lds16(W2bf + (size_t)row * NCMID + k0 + ks * 8,
               &sB[buf][0][0] + (c * 256 + wave * 64) * 8);
    }
  };
  auto stageA = [&](int buf, int kt) {
    const int k0 = kt * 32;
#pragma unroll
    for (int c = 0; c < 2; ++c) {
      const int s = c * 256 + tid;
      const int row = s >> 2, c16 = s & 3;
      const int ks = c16 ^ ((row >> 1) & 3);
      const int k = k0 + ks * 8;
      PK8 v;
      v.q = *(const uint4*)(h1bf + (size_t)(ptBase + row) * NCMID + k);
      PK8 pk;
#pragma unroll
      for (int j = 0; j < 8; ++j)
        pk.u[j] = f2bf(fmaxf(0.f, sa[k + j] * bf2f(v.u[j]) + sd[k + j]));
      *(uint4*)(&sA[buf][0][0] + s * 8) = pk.q;
    }
  };

  stageB(0, 0);
  __syncthreads();
  stageA(0, 0);
  __syncthreads();
  int cur = 0;
  for (int kt = 0; kt < 8; ++kt) {
    if (kt < 7) { stageB(cur ^ 1, kt + 1); stageA(cur ^ 1, kt + 1); }
    const bf16x8 a0 = *(const bf16x8*)&sA[cur][wave * 32 + fr][rdsh];
    const bf16x8 a1 = *(const bf16x8*)&sA[cur][wave * 32 + 16 + fr][rdsh];
#pragma unroll
    for (int j = 0; j < 8; ++j) {
      const bf16x8 b = *(const bf16x8*)&sB[cur][j * 16 + fr][rdsh];
      acc[0][j] = __builtin_amdgcn_mfma_f32_16x16x32_bf16(a0, b, acc[0][j], 0, 0, 0);
      acc[1][j] = __builtin_amdgcn_mfma_f32_16x16x32_bf16(a1, b, acc[1][j], 0, 0, 0);
    }
    __syncthreads();
    cur ^= 1;
  }

  float* redS = (float*)&sA[0][0][0];
  float* redQ = redS + 512;
  const int col = fr;
  const int r0 = cs * 4;
#pragma unroll
  for (int j = 0; j < 8; ++j) {
    const int ch = j * 16 + col;
    const float bb = bias2[ch];
    float s = 0.f, s2 = 0.f;
#pragma unroll
    for (int m = 0; m < 2; ++m)
#pragma unroll
      for (int q = 0; q < 4; ++q) {
        const int pt = ptBase + wave * 32 + m * 16 + r0 + q;
        const float v = acc[m][j][q] + bb;
        h2bf[(size_t)pt * NCOUT + ch] = f2bf(v);
        s += v; s2 += v * v;
      }
    s += __shfl_xor(s, 16);  s2 += __shfl_xor(s2, 16);
    s += __shfl_xor(s, 32);  s2 += __shfl_xor(s2, 32);
    if (cs == 0) { redS[wave * 128 + fr * 8 + j] = s; redQ[wave * 128 + fr * 8 + j] = s2; }
  }
  __syncthreads();
  if (tid < NCOUT) {
    const int ch = tid;
    const int f = ch & 15, j = ch >> 4;
    float s = 0.f, s2 = 0.f;
#pragma unroll
    for (int w = 0; w < 4; ++w) {
      s  += redS[w * 128 + f * 8 + j];
      s2 += redQ[w * 128 + f * 8 + j];
    }
    atomicAdd(&sum2[ch], s);
    atomicAdd(&sq2[ch], s2);
  }
}

// ---------------- final: BN2-affine + ReLU, bf16 h2 -> fp32 out ----------------
__global__ __launch_bounds__(256) void final_kernel(
    const unsigned short* __restrict__ h2bf, float* __restrict__ out,
    const float* __restrict__ a2, const float* __restrict__ d2)
{
  __shared__ float sa[NCOUT], sd[NCOUT];
  if (threadIdx.x < NCOUT) { sa[threadIdx.x] = a2[threadIdx.x]; sd[threadIdx.x] = d2[threadIdx.x]; }
  __syncthreads();
  const int total8 = BNTOT * NCOUT / 8;   // 1,048,576 chunks of 8
  for (int i = blockIdx.x * blockDim.x + threadIdx.x; i < total8;
       i += gridDim.x * blockDim.x) {
    PK8 v; v.q = ((const uint4*)h2bf)[i];
    const int c = (i & 15) * 8;
    float4 o0, o1;
    o0.x = fmaxf(0.f, sa[c + 0] * bf2f(v.u[0]) + sd[c + 0]);
    o0.y = fmaxf(0.f, sa[c + 1] * bf2f(v.u[1]) + sd[c + 1]);
    o0.z = fmaxf(0.f, sa[c + 2] * bf2f(v.u[2]) + sd[c + 2]);
    o0.w = fmaxf(0.f, sa[c + 3] * bf2f(v.u[3]) + sd[c + 3]);
    o1.x = fmaxf(0.f, sa[c + 4] * bf2f(v.u[4]) + sd[c + 4]);
    o1.y = fmaxf(0.f, sa[c + 5] * bf2f(v.u[5]) + sd[c + 5]);
    o1.z = fmaxf(0.f, sa[c + 6] * bf2f(v.u[6]) + sd[c + 6]);
    o1.w = fmaxf(0.f, sa[c + 7] * bf2f(v.u[7]) + sd[c + 7]);
    ((float4*)out)[i * 2]     = o0;
    ((float4*)out)[i * 2 + 1] = o1;
  }
}

extern "C" void kernel_launch(void* const* d_in, const int* in_sizes, int n_in,
                              void* d_out, int out_size, void* d_ws, size_t ws_size,
                              hipStream_t stream) {
  const float* xyz1    = (const float*)d_in[0];
  const float* xyz2    = (const float*)d_in[1];
  const float* points1 = (const float*)d_in[2];
  const float* points2 = (const float*)d_in[3];
  const float* W1      = (const float*)d_in[4];
  const float* b1      = (const float*)d_in[5];
  const float* g1      = (const float*)d_in[6];
  const float* be1     = (const float*)d_in[7];
  const float* W2      = (const float*)d_in[8];
  const float* b2      = (const float*)d_in[9];
  const float* g2      = (const float*)d_in[10];
  const float* be2     = (const float*)d_in[11];
  float* out = (float*)d_out;

  char* ws = (char*)d_ws;
  const size_t xbf_bytes = (size_t)BNTOT * NCIN * 2;     // 48 MB
  const size_t h1_bytes  = (size_t)BNTOT * NCMID * 2;    // 32 MB
  const size_t h2_bytes  = (size_t)BNTOT * NCOUT * 2;    // 16 MB
  const size_t w1b_bytes = (size_t)NCMID * NCIN * 2;     // 192 KB
  const size_t w2b_bytes = (size_t)NCOUT * NCMID * 2;    // 64 KB
  unsigned short* Xbf  = (unsigned short*)ws;
  unsigned short* h1bf = (unsigned short*)(ws + xbf_bytes);
  unsigned short* h2bf = (unsigned short*)(ws + xbf_bytes + h1_bytes);
  unsigned short* W1bf = (unsigned short*)(ws + xbf_bytes + h1_bytes + h2_bytes);
  unsigned short* W2bf = (unsigned short*)(ws + xbf_bytes + h1_bytes + h2_bytes + w1b_bytes);
  float* stats = (float*)(ws + xbf_bytes + h1_bytes + h2_bytes + w1b_bytes + w2b_bytes);
  float* sum1 = stats;
  float* sq1  = stats + 256;
  float* sum2 = stats + 512;
  float* sq2  = stats + 640;
  float* a1   = stats + 768;
  float* dd1  = stats + 1024;
  float* a2v  = stats + 1280;
  float* dd2v = stats + 1408;

  hipMemsetAsync(stats, 0, 768 * sizeof(float), stream);

  prep_w_kernel<<<128, 256, 0, stream>>>(W1, W2, W1bf, W2bf);
  front_kernel<<<BNTOT / 32, 256, 0, stream>>>(xyz1, xyz2, points1, points2, Xbf);
  gemm1_kernel<<<BNTOT / 128, 256, 0, stream>>>(Xbf, W1bf, b1, h1bf, sum1, sq1);
  stats_kernel<NCMID><<<1, NCMID, 0, stream>>>(sum1, sq1, g1, be1, a1, dd1);
  gemm2_kernel<<<BNTOT / 128, 256, 0, stream>>>(h1bf, W2bf, b2, a1, dd1, h2bf, sum2, sq2);
  stats_kernel<NCOUT><<<1, NCOUT, 0, stream>>>(sum2, sq2, g2, be2, a2v, dd2v);
  final_kernel<<<2048, 256, 0, stream>>>(h2bf, out, a2v, dd2v);
}

// Round 6
// 124.522 us; speedup vs baseline: 2.5658x; 1.2086x over previous
//
#include <hip/hip_runtime.h>
#include <hip/hip_bf16.h>

#define NB    16
#define NPT   4096
#define NSRC  1024
#define ND1   128
#define ND2   256
#define NCIN  384
#define NCMID 256
#define NCOUT 128
#define BNTOT (NB * NPT)   // 65536 points
#define BN_EPS 1e-5f

typedef float f32x4 __attribute__((ext_vector_type(4)));
typedef short bf16x8 __attribute__((ext_vector_type(8)));
typedef unsigned int uint;

union PK8 { unsigned short u[8]; uint4 q; };
union PK4 { unsigned short u[4]; uint2 q; };

static __device__ __forceinline__ unsigned short f2bf(float f) {
  __hip_bfloat16 h = __float2bfloat16(f);
  return __builtin_bit_cast(unsigned short, h);
}
static __device__ __forceinline__ float bf2f(unsigned short u) {
  return __builtin_bit_cast(float, (uint)u << 16);
}
static __device__ __forceinline__ void gl_lds16(const unsigned short* g, unsigned short* l) {
  __builtin_amdgcn_global_load_lds(
      (const __attribute__((address_space(1))) uint*)(const void*)g,
      (__attribute__((address_space(3))) uint*)(void*)l,
      16, 0, 0);
}

#if __has_builtin(__builtin_amdgcn_fmed3f)
#define MED3F(a, b, c) __builtin_amdgcn_fmed3f((a), (b), (c))
#else
#define MED3F(a, b, c) fmaxf((a), fminf((b), (c)))
#endif

// total order: (d, idx) with ties -> lower index (matches lax.top_k)
static __device__ __forceinline__ bool prec(float da, int ia, float db, int ib) {
  return (da < db) || (da == db && ia < ib);
}

// shallow branchless top-3 insert (proven round 5)
#define INSV(t0, t1, t2, j0, j1, j2, d, idx)                                   \
  {                                                                            \
    const bool c0 = (d) < t0;                                                  \
    const bool c1 = (d) < t1;                                                  \
    const bool c2 = (d) < t2;                                                  \
    const float m1 = MED3F(t0, t1, (d));                                       \
    const float m2 = fminf(t2, fmaxf(t1, (d)));                                \
    t0 = fminf(t0, (d));                                                       \
    j2 = c2 ? (c1 ? j1 : (idx)) : j2;                                          \
    j1 = c1 ? (c0 ? j0 : (idx)) : j1;                                          \
    j0 = c0 ? (idx) : j0;                                                      \
    t1 = m1; t2 = m2;                                                          \
  }

#define MERGE3(d0, j0, d1, j1, d2, j2, e0, i0, e1, i1, e2, i2)                 \
  {                                                                            \
    const bool p0 = prec(d0, j0, e0, i0);                                      \
    const float l0d = p0 ? e0 : d0; const int l0j = p0 ? i0 : j0;              \
    const float r0d = p0 ? d0 : e0; const int r0j = p0 ? j0 : i0;              \
    const bool p1 = prec(d1, j1, e1, i1);                                      \
    const float w1d = p1 ? d1 : e1; const int w1j = p1 ? j1 : i1;              \
    const bool pr1 = prec(l0d, l0j, w1d, w1j);                                 \
    const float r1d = pr1 ? l0d : w1d; const int r1j = pr1 ? l0j : w1j;        \
    const float q1d = pr1 ? w1d : l0d; const int q1j = pr1 ? w1j : l0j;        \
    const bool p2 = prec(d2, j2, e2, i2);                                      \
    const float w2d = p2 ? d2 : e2; const int w2j = p2 ? j2 : i2;              \
    const bool pr2 = prec(q1d, q1j, w2d, w2j);                                 \
    const float r2d = pr2 ? q1d : w2d; const int r2j = pr2 ? q1j : w2j;        \
    d0 = r0d; j0 = r0j; d1 = r1d; j1 = r1j; d2 = r2d; j2 = r2j;                \
  }

// ---------------- prep: W1,W2 fp32 -> bf16 ----------------
__global__ __launch_bounds__(256) void prep_w_kernel(
    const float* __restrict__ w1, const float* __restrict__ w2,
    unsigned short* __restrict__ w1b, unsigned short* __restrict__ w2b)
{
  const int i = blockIdx.x * 256 + threadIdx.x;
  const bool isW1 = i < 24576;
  const float4 v = isW1 ? ((const float4*)w1)[i] : ((const float4*)w2)[i - 24576];
  PK4 pk;
  pk.u[0] = f2bf(v.x); pk.u[1] = f2bf(v.y); pk.u[2] = f2bf(v.z); pk.u[3] = f2bf(v.w);
  if (isW1) ((uint2*)w1b)[i] = pk.q;
  else      ((uint2*)w2b)[i - 24576] = pk.q;
}

// ================= fused kNN + interp + GEMM1 (+BN1 colsums) =================
// 512 threads (8 waves), 128 points/block, grid 512. K=384 in 12 kt steps.
// A-tile built in LDS on the fly (points1 cast for kt<4, 3-NN gather for kt>=4);
// B via global_load_lds double-buffered. Wave w computes pts [16w,16w+16) x 256 ch.
__global__ __launch_bounds__(512, 4) void fg1_kernel(
    const float* __restrict__ xyz1, const float* __restrict__ xyz2,
    const float* __restrict__ points1, const float* __restrict__ points2,
    const unsigned short* __restrict__ W1bf, const float* __restrict__ bias1,
    unsigned short* __restrict__ h1bf, float* __restrict__ sum1, float* __restrict__ sq1)
{
  __shared__ unsigned short sA[2][128][32];   // 16 KB (overlaid by redS/redQ in epilogue)
  __shared__ unsigned short sB[2][256][32];   // 32 KB
  __shared__ float4 s2t[4 * 257];             // 16.4 KB transformed xyz2
  __shared__ int   sj[128][3];
  __shared__ float sw[128][3];

  const int tid = threadIdx.x;
  const int lane = tid & 63;
  const int wave = tid >> 6;
  const int ptBase = blockIdx.x * 128;
  const int b = ptBase >> 12;                 // 32 blocks per batch, no straddle

  const int fr = lane & 15;
  const int cs = lane >> 4;
  const int rdsh = ((cs ^ ((fr >> 1) & 3)) << 3);

  // ---- B staging: 1024 slots of 16B, 2 chunks of 512 (wave-uniform bases) ----
  auto stageB = [&](int buf, int kt) {
    const int k0 = kt * 32;
#pragma unroll
    for (int c = 0; c < 2; ++c) {
      const int base = c * 512 + wave * 64;
      const int s = base + lane;
      const int row = s >> 2, c16 = s & 3;
      const int ks = c16 ^ ((row >> 1) & 3);
      gl_lds16(W1bf + (size_t)row * NCIN + k0 + ks * 8,
               &sB[buf][0][0] + base * 8);
    }
  };

  // ---- A staging: 512 slots of 16B, thread t = slot; branch is kt-uniform ----
  auto stageA = [&](int buf, int kt) {
    const int k0 = kt * 32;
    const int row = tid >> 2, c16 = tid & 3;
    const int ks = c16 ^ ((row >> 1) & 3);
    const int k = k0 + ks * 8;
    PK8 pk;
    if (k < ND1) {                            // kt 0..3: cast points1
      const float* src = points1 + (size_t)(ptBase + row) * ND1 + k;
      const float4 va = ((const float4*)src)[0];
      const float4 vb = ((const float4*)src)[1];
      pk.u[0] = f2bf(va.x); pk.u[1] = f2bf(va.y); pk.u[2] = f2bf(va.z); pk.u[3] = f2bf(va.w);
      pk.u[4] = f2bf(vb.x); pk.u[5] = f2bf(vb.y); pk.u[6] = f2bf(vb.z); pk.u[7] = f2bf(vb.w);
    } else {                                  // kt 4..11: 3-NN gather + combine
      const float* p2 = points2 + (size_t)b * NSRC * ND2 + (k - ND1);
      const int j0 = sj[row][0], j1 = sj[row][1], j2 = sj[row][2];
      const float w0 = sw[row][0], w1 = sw[row][1], w2 = sw[row][2];
      const float4* r0 = (const float4*)(p2 + (size_t)j0 * ND2);
      const float4* r1 = (const float4*)(p2 + (size_t)j1 * ND2);
      const float4* r2 = (const float4*)(p2 + (size_t)j2 * ND2);
#pragma unroll
      for (int h = 0; h < 2; ++h) {
        const float4 va = r0[h], vb = r1[h], vc = r2[h];
        pk.u[h * 4 + 0] = f2bf(w0 * va.x + w1 * vb.x + w2 * vc.x);
        pk.u[h * 4 + 1] = f2bf(w0 * va.y + w1 * vb.y + w2 * vc.y);
        pk.u[h * 4 + 2] = f2bf(w0 * va.z + w1 * vb.z + w2 * vc.z);
        pk.u[h * 4 + 3] = f2bf(w0 * va.w + w1 * vb.w + w2 * vc.w);
      }
    }
    *(uint4*)(&sA[buf][0][0] + tid * 8) = pk.q;
  };

  // ---- phase 0: prefetch B0, stage s2t, stage A0 (points1-only) ----
  stageB(0, 0);
  if (tid < 256) {
    const float* src = xyz2 + (size_t)b * NSRC * 3 + tid * 12;
    const float4 l0 = ((const float4*)src)[0];
    const float4 l1 = ((const float4*)src)[1];
    const float4 l2 = ((const float4*)src)[2];
    const float xs[4] = {l0.x, l0.w, l1.z, l2.y};
    const float ys[4] = {l0.y, l1.x, l1.w, l2.z};
    const float zs[4] = {l0.z, l1.y, l2.x, l2.w};
    const int qq = tid >> 6;
    const int ibase = (tid & 63) * 4;
#pragma unroll
    for (int u = 0; u < 4; ++u) {
      const float c = xs[u] * xs[u] + ys[u] * ys[u] + zs[u] * zs[u];
      float4 v;
      v.x = -2.0f * xs[u]; v.y = -2.0f * ys[u]; v.z = -2.0f * zs[u]; v.w = c;
      s2t[qq * 257 + ibase + u] = v;
    }
  }
  stageA(0, 0);
  __syncthreads();

  // ---- phase 1: kNN (4 lanes/pt x 256 sources; proven round-4/5 core) ----
  {
    const int ptl = tid >> 2;                 // 0..127
    const int q = tid & 3;
    const int p = ptBase + ptl;
    const float ax = xyz1[(size_t)p * 3 + 0];
    const float ay = xyz1[(size_t)p * 3 + 1];
    const float az = xyz1[(size_t)p * 3 + 2];
    const float a2 = ax * ax + ay * ay + az * az;
    const float4* slab = &s2t[q * 257];
    const int qbase = q * 256;

    const float INF = 3.4e38f;
    float ta0 = INF, ta1 = INF, ta2 = INF; int ja0 = 0, ja1 = 0, ja2 = 0;
    float tb0 = INF, tb1 = INF, tb2 = INF; int jb0 = 0, jb1 = 0, jb2 = 0;

    for (int i = 0; i < 256; i += 2) {
      const float4 va = slab[i];
      float da = va.w + a2;
      da = fmaf(va.x, ax, da); da = fmaf(va.y, ay, da); da = fmaf(va.z, az, da);
      INSV(ta0, ta1, ta2, ja0, ja1, ja2, da, qbase + i);
      const float4 vb = slab[i + 1];
      float db = vb.w + a2;
      db = fmaf(vb.x, ax, db); db = fmaf(vb.y, ay, db); db = fmaf(vb.z, az, db);
      INSV(tb0, tb1, tb2, jb0, jb1, jb2, db, qbase + i + 1);
    }
    MERGE3(ta0, ja0, ta1, ja1, ta2, ja2, tb0, jb0, tb1, jb1, tb2, jb2);

#pragma unroll
    for (int m = 1; m <= 2; m <<= 1) {
      float e0 = __shfl_xor(ta0, m), e1 = __shfl_xor(ta1, m), e2 = __shfl_xor(ta2, m);
      int i0 = __shfl_xor(ja0, m), i1 = __shfl_xor(ja1, m), i2 = __shfl_xor(ja2, m);
      MERGE3(ta0, ja0, ta1, ja1, ta2, ja2, e0, i0, e1, i1, e2, i2);
    }

    if (q == 0) {
      float w0 = 1.f / (ta0 + 1e-8f), w1 = 1.f / (ta1 + 1e-8f), w2 = 1.f / (ta2 + 1e-8f);
      const float inv = 1.f / (w0 + w1 + w2);
      sj[ptl][0] = ja0; sj[ptl][1] = ja1; sj[ptl][2] = ja2;
      sw[ptl][0] = w0 * inv; sw[ptl][1] = w1 * inv; sw[ptl][2] = w2 * inv;
    }
  }
  __syncthreads();

  // ---- phase 2: K-loop ----
  f32x4 acc[16];
#pragma unroll
  for (int j = 0; j < 16; ++j)
#pragma unroll
    for (int q = 0; q < 4; ++q) acc[j][q] = 0.0f;

  int cur = 0;
  for (int kt = 0; kt < 12; ++kt) {
    if (kt < 11) { stageB(cur ^ 1, kt + 1); stageA(cur ^ 1, kt + 1); }
    const bf16x8 a = *(const bf16x8*)&sA[cur][wave * 16 + fr][rdsh];
#pragma unroll
    for (int j = 0; j < 16; ++j) {
      const bf16x8 bv = *(const bf16x8*)&sB[cur][j * 16 + fr][rdsh];
      acc[j] = __builtin_amdgcn_mfma_f32_16x16x32_bf16(a, bv, acc[j], 0, 0, 0);
    }
    __syncthreads();
    cur ^= 1;
  }

  // ---- epilogue: h1bf store + BN1 partial sums ----
  float* redS = (float*)&sA[0][0][0];         // 8 KB
  float* redQ = redS + 2048;                  // 8 KB (fills rest of sA)
  const int r0 = cs * 4;
#pragma unroll
  for (int j = 0; j < 16; ++j) {
    const int ch = j * 16 + fr;
    const float bb = bias1[ch];
    float s = 0.f, s2 = 0.f;
#pragma unroll
    for (int q = 0; q < 4; ++q) {
      const int pt = ptBase + wave * 16 + r0 + q;
      const float v = acc[j][q] + bb;
      h1bf[(size_t)pt * NCMID + ch] = f2bf(v);
      s += v; s2 += v * v;
    }
    s += __shfl_xor(s, 16);  s2 += __shfl_xor(s2, 16);
    s += __shfl_xor(s, 32);  s2 += __shfl_xor(s2, 32);
    if (cs == 0) { redS[wave * 256 + ch] = s; redQ[wave * 256 + ch] = s2; }
  }
  __syncthreads();
  if (tid < NCMID) {
    float s = 0.f, s2 = 0.f;
#pragma unroll
    for (int w = 0; w < 8; ++w) {
      s  += redS[w * 256 + tid];
      s2 += redQ[w * 256 + tid];
    }
    atomicAdd(&sum1[tid], s);
    atomicAdd(&sq1[tid], s2);
  }
}

// ---------------- fold BN into per-channel affine: y = a*x + d ----------------
template <int C>
__global__ void stats_kernel(const float* __restrict__ sum, const float* __restrict__ sumsq,
                             const float* __restrict__ g, const float* __restrict__ be,
                             float* __restrict__ a, float* __restrict__ d)
{
  const int c = threadIdx.x;
  const float mean = sum[c] * (1.0f / BNTOT);
  const float var = sumsq[c] * (1.0f / BNTOT) - mean * mean;
  const float inv = rsqrtf(var + BN_EPS);
  const float ac = g[c] * inv;
  a[c] = ac;
  d[c] = be[c] - mean * ac;
}

// ---------------- GEMM2 (+fused BN2 column sums, bf16 out) ----------------
__global__ __launch_bounds__(256, 2) void gemm2_kernel(
    const unsigned short* __restrict__ h1bf, const unsigned short* __restrict__ W2bf,
    const float* __restrict__ bias2, const float* __restrict__ aff_a,
    const float* __restrict__ aff_d, unsigned short* __restrict__ h2bf,
    float* __restrict__ sum2, float* __restrict__ sq2)
{
  __shared__ unsigned short sA[2][128][32];
  __shared__ unsigned short sB[2][128][32];
  __shared__ float sa[NCMID], sd[NCMID];
  const int tid = threadIdx.x;
  const int lane = tid & 63;
  const int wave = tid >> 6;
  const int ptBase = blockIdx.x * 128;
  sa[tid] = aff_a[tid];
  sd[tid] = aff_d[tid];

  f32x4 acc[2][8];
#pragma unroll
  for (int m = 0; m < 2; ++m)
#pragma unroll
    for (int j = 0; j < 8; ++j)
#pragma unroll
      for (int q = 0; q < 4; ++q) acc[m][j][q] = 0.0f;

  const int fr = lane & 15;
  const int cs = lane >> 4;
  const int rdsh = ((cs ^ ((fr >> 1) & 3)) << 3);

  auto stageB = [&](int buf, int kt) {
    const int k0 = kt * 32;
#pragma unroll
    for (int c = 0; c < 2; ++c) {
      const int s = c * 256 + wave * 64 + lane;
      const int row = s >> 2, c16 = s & 3;
      const int ks = c16 ^ ((row >> 1) & 3);
      gl_lds16(W2bf + (size_t)row * NCMID + k0 + ks * 8,
               &sB[buf][0][0] + (c * 256 + wave * 64) * 8);
    }
  };
  auto stageA = [&](int buf, int kt) {
    const int k0 = kt * 32;
#pragma unroll
    for (int c = 0; c < 2; ++c) {
      const int s = c * 256 + tid;
      const int row = s >> 2, c16 = s & 3;
      const int ks = c16 ^ ((row >> 1) & 3);
      const int k = k0 + ks * 8;
      PK8 v;
      v.q = *(const uint4*)(h1bf + (size_t)(ptBase + row) * NCMID + k);
      PK8 pk;
#pragma unroll
      for (int j = 0; j < 8; ++j)
        pk.u[j] = f2bf(fmaxf(0.f, sa[k + j] * bf2f(v.u[j]) + sd[k + j]));
      *(uint4*)(&sA[buf][0][0] + s * 8) = pk.q;
    }
  };

  stageB(0, 0);
  __syncthreads();
  stageA(0, 0);
  __syncthreads();
  int cur = 0;
  for (int kt = 0; kt < 8; ++kt) {
    if (kt < 7) { stageB(cur ^ 1, kt + 1); stageA(cur ^ 1, kt + 1); }
    const bf16x8 a0 = *(const bf16x8*)&sA[cur][wave * 32 + fr][rdsh];
    const bf16x8 a1 = *(const bf16x8*)&sA[cur][wave * 32 + 16 + fr][rdsh];
#pragma unroll
    for (int j = 0; j < 8; ++j) {
      const bf16x8 b = *(const bf16x8*)&sB[cur][j * 16 + fr][rdsh];
      acc[0][j] = __builtin_amdgcn_mfma_f32_16x16x32_bf16(a0, b, acc[0][j], 0, 0, 0);
      acc[1][j] = __builtin_amdgcn_mfma_f32_16x16x32_bf16(a1, b, acc[1][j], 0, 0, 0);
    }
    __syncthreads();
    cur ^= 1;
  }

  float* redS = (float*)&sA[0][0][0];
  float* redQ = redS + 512;
  const int col = fr;
  const int r0 = cs * 4;
#pragma unroll
  for (int j = 0; j < 8; ++j) {
    const int ch = j * 16 + col;
    const float bb = bias2[ch];
    float s = 0.f, s2 = 0.f;
#pragma unroll
    for (int m = 0; m < 2; ++m)
#pragma unroll
      for (int q = 0; q < 4; ++q) {
        const int pt = ptBase + wave * 32 + m * 16 + r0 + q;
        const float v = acc[m][j][q] + bb;
        h2bf[(size_t)pt * NCOUT + ch] = f2bf(v);
        s += v; s2 += v * v;
      }
    s += __shfl_xor(s, 16);  s2 += __shfl_xor(s2, 16);
    s += __shfl_xor(s, 32);  s2 += __shfl_xor(s2, 32);
    if (cs == 0) { redS[wave * 128 + fr * 8 + j] = s; redQ[wave * 128 + fr * 8 + j] = s2; }
  }
  __syncthreads();
  if (tid < NCOUT) {
    const int ch = tid;
    const int f = ch & 15, j = ch >> 4;
    float s = 0.f, s2 = 0.f;
#pragma unroll
    for (int w = 0; w < 4; ++w) {
      s  += redS[w * 128 + f * 8 + j];
      s2 += redQ[w * 128 + f * 8 + j];
    }
    atomicAdd(&sum2[ch], s);
    atomicAdd(&sq2[ch], s2);
  }
}

// ---------------- final: BN2-affine + ReLU, bf16 h2 -> fp32 out ----------------
__global__ __launch_bounds__(256) void final_kernel(
    const unsigned short* __restrict__ h2bf, float* __restrict__ out,
    const float* __restrict__ a2, const float* __restrict__ d2)
{
  __shared__ float sa[NCOUT], sd[NCOUT];
  if (threadIdx.x < NCOUT) { sa[threadIdx.x] = a2[threadIdx.x]; sd[threadIdx.x] = d2[threadIdx.x]; }
  __syncthreads();
  const int total8 = BNTOT * NCOUT / 8;
  for (int i = blockIdx.x * blockDim.x + threadIdx.x; i < total8;
       i += gridDim.x * blockDim.x) {
    PK8 v; v.q = ((const uint4*)h2bf)[i];
    const int c = (i & 15) * 8;
    float4 o0, o1;
    o0.x = fmaxf(0.f, sa[c + 0] * bf2f(v.u[0]) + sd[c + 0]);
    o0.y = fmaxf(0.f, sa[c + 1] * bf2f(v.u[1]) + sd[c + 1]);
    o0.z = fmaxf(0.f, sa[c + 2] * bf2f(v.u[2]) + sd[c + 2]);
    o0.w = fmaxf(0.f, sa[c + 3] * bf2f(v.u[3]) + sd[c + 3]);
    o1.x = fmaxf(0.f, sa[c + 4] * bf2f(v.u[4]) + sd[c + 4]);
    o1.y = fmaxf(0.f, sa[c + 5] * bf2f(v.u[5]) + sd[c + 5]);
    o1.z = fmaxf(0.f, sa[c + 6] * bf2f(v.u[6]) + sd[c + 6]);
    o1.w = fmaxf(0.f, sa[c + 7] * bf2f(v.u[7]) + sd[c + 7]);
    ((float4*)out)[i * 2]     = o0;
    ((float4*)out)[i * 2 + 1] = o1;
  }
}

extern "C" void kernel_launch(void* const* d_in, const int* in_sizes, int n_in,
                              void* d_out, int out_size, void* d_ws, size_t ws_size,
                              hipStream_t stream) {
  const float* xyz1    = (const float*)d_in[0];
  const float* xyz2    = (const float*)d_in[1];
  const float* points1 = (const float*)d_in[2];
  const float* points2 = (const float*)d_in[3];
  const float* W1      = (const float*)d_in[4];
  const float* b1      = (const float*)d_in[5];
  const float* g1      = (const float*)d_in[6];
  const float* be1     = (const float*)d_in[7];
  const float* W2      = (const float*)d_in[8];
  const float* b2      = (const float*)d_in[9];
  const float* g2      = (const float*)d_in[10];
  const float* be2     = (const float*)d_in[11];
  float* out = (float*)d_out;

  char* ws = (char*)d_ws;
  const size_t h1_bytes  = (size_t)BNTOT * NCMID * 2;    // 32 MB
  const size_t h2_bytes  = (size_t)BNTOT * NCOUT * 2;    // 16 MB
  const size_t w1b_bytes = (size_t)NCMID * NCIN * 2;     // 192 KB
  const size_t w2b_bytes = (size_t)NCOUT * NCMID * 2;    // 64 KB
  unsigned short* h1bf = (unsigned short*)ws;
  unsigned short* h2bf = (unsigned short*)(ws + h1_bytes);
  unsigned short* W1bf = (unsigned short*)(ws + h1_bytes + h2_bytes);
  unsigned short* W2bf = (unsigned short*)(ws + h1_bytes + h2_bytes + w1b_bytes);
  float* stats = (float*)(ws + h1_bytes + h2_bytes + w1b_bytes + w2b_bytes);
  float* sum1 = stats;
  float* sq1  = stats + 256;
  float* sum2 = stats + 512;
  float* sq2  = stats + 640;
  float* a1   = stats + 768;
  float* dd1  = stats + 1024;
  float* a2v  = stats + 1280;
  float* dd2v = stats + 1408;

  hipMemsetAsync(stats, 0, 768 * sizeof(float), stream);

  prep_w_kernel<<<128, 256, 0, stream>>>(W1, W2, W1bf, W2bf);
  fg1_kernel<<<BNTOT / 128, 512, 0, stream>>>(xyz1, xyz2, points1, points2,
                                              W1bf, b1, h1bf, sum1, sq1);
  stats_kernel<NCMID><<<1, NCMID, 0, stream>>>(sum1, sq1, g1, be1, a1, dd1);
  gemm2_kernel<<<BNTOT / 128, 256, 0, stream>>>(h1bf, W2bf, b2, a1, dd1, h2bf, sum2, sq2);
  stats_kernel<NCOUT><<<1, NCOUT, 0, stream>>>(sum2, sq2, g2, be2, a2v, dd2v);
  final_kernel<<<2048, 256, 0, stream>>>(h2bf, out, a2v, dd2v);
}